// Round 2
// baseline (995.878 us; speedup 1.0000x reference)
//
#include <hip/hip_runtime.h>
#include <hip/hip_fp16.h>

constexpr int IN_DIM  = 256;
constexpr int HID_DIM = 128;
constexpr int OUT_DIM = 64;

constexpr int NPB_SHIFT = 8;          // 256 nodes per bucket
constexpr int NPB   = 1 << NPB_SHIFT;
constexpr int NBMAX = 512;            // max buckets supported in LDS tables
constexpr int CHUNK = 4096;           // edges per binning block
constexpr int CAP_B = 12288;          // LDS col-stage capacity (48 KB)

typedef _Float16 half8 __attribute__((ext_vector_type(8)));
typedef float floatx4 __attribute__((ext_vector_type(4)));

// ---------------- misc ----------------

__global__ __launch_bounds__(256) void k_zero(int* __restrict__ p, int n) {
  int i = blockIdx.x * 256 + threadIdx.x;
  if (i < n) p[i] = 0;
}

// ---------------- CSR build via bucketed counting sort ----------------

__global__ __launch_bounds__(256) void k_hist(const int* __restrict__ dst, int E, int NB,
                                              int* __restrict__ bsize) {
  __shared__ int h[NBMAX];
  for (int i = threadIdx.x; i < NB; i += 256) h[i] = 0;
  __syncthreads();
  int e0 = blockIdx.x * CHUNK;
  int e1 = min(e0 + CHUNK, E);
  for (int e = e0 + threadIdx.x; e < e1; e += 256) {
    int d = __builtin_nontemporal_load(&dst[e]);
    atomicAdd(&h[d >> NPB_SHIFT], 1);
  }
  __syncthreads();
  for (int b = threadIdx.x; b < NB; b += 256) {
    int c = h[b];
    if (c) atomicAdd(&bsize[b], c);
  }
}

__global__ __launch_bounds__(512) void k_scanb(const int* __restrict__ bsize, int NB, int E,
                                               int* __restrict__ boff, int* __restrict__ gcur) {
  __shared__ int sh[NBMAX + 1];
  for (int i = threadIdx.x; i < NB; i += 512) sh[i] = bsize[i];
  __syncthreads();
  if (threadIdx.x == 0) {
    int run = 0;
    for (int b = 0; b < NB; b++) { int v = sh[b]; sh[b] = run; run += v; }
    sh[NB] = run;
  }
  __syncthreads();
  for (int i = threadIdx.x; i < NB; i += 512) { boff[i] = sh[i]; gcur[i] = sh[i]; }
  if (threadIdx.x == 0) boff[NB] = sh[NB];
}

__global__ __launch_bounds__(256) void k_binA(const int* __restrict__ src,
                                              const int* __restrict__ dst, int E, int NB,
                                              int* __restrict__ gcur,
                                              unsigned long long* __restrict__ bin) {
  __shared__ unsigned long long sbuf[CHUNK];  // 32 KB
  __shared__ int h[NBMAX], lofs[NBMAX], wofs[NBMAX], hcur[NBMAX];
  for (int i = threadIdx.x; i < NB; i += 256) h[i] = 0;
  __syncthreads();
  int e0 = blockIdx.x * CHUNK;
  int e1 = min(e0 + CHUNK, E);
  for (int e = e0 + threadIdx.x; e < e1; e += 256) {
    int d = __builtin_nontemporal_load(&dst[e]);
    atomicAdd(&h[d >> NPB_SHIFT], 1);
  }
  __syncthreads();
  for (int b = threadIdx.x; b < NB; b += 256) {
    int c = h[b];
    if (c) wofs[b] = atomicAdd(&gcur[b], c);
  }
  if (threadIdx.x == 0) {
    int run = 0;
    for (int b = 0; b < NB; b++) { lofs[b] = run; run += h[b]; }
  }
  __syncthreads();
  for (int b = threadIdx.x; b < NB; b += 256) hcur[b] = lofs[b];
  __syncthreads();
  for (int e = e0 + threadIdx.x; e < e1; e += 256) {
    int d = dst[e];
    int s = src[e];
    int b = d >> NPB_SHIFT;
    int p = atomicAdd(&hcur[b], 1);
    sbuf[p] = ((unsigned long long)(unsigned)d << 32) | (unsigned)s;
  }
  __syncthreads();
  int total = e1 - e0;
  for (int i = threadIdx.x; i < total; i += 256) {
    unsigned long long v = sbuf[i];
    int b = (int)(v >> 32) >> NPB_SHIFT;
    bin[(size_t)wofs[b] + (i - lofs[b])] = v;
  }
}

__global__ __launch_bounds__(256) void k_passB(const unsigned long long* __restrict__ bin,
                                               const int* __restrict__ boff, int NB, int N, int E,
                                               int* __restrict__ rowptr, float* __restrict__ dis,
                                               int* __restrict__ col) {
  __shared__ unsigned int colbuf[CAP_B];  // 48 KB
  __shared__ int lcnt[NPB], lofs2[NPB + 1], lpos[NPB];
  int b = blockIdx.x;
  int lo = b << NPB_SHIFT;
  int e0 = boff[b], e1 = boff[b + 1];
  int tot = e1 - e0;
  if (threadIdx.x < NPB) lcnt[threadIdx.x] = 0;
  __syncthreads();
  for (int i = threadIdx.x; i < tot; i += 256) {
    unsigned long long v = bin[(size_t)e0 + i];
    atomicAdd(&lcnt[(int)(v >> 32) & (NPB - 1)], 1);
  }
  __syncthreads();
  if (threadIdx.x == 0) {
    int run = 0;
    for (int i = 0; i < NPB; i++) { lofs2[i] = run; run += lcnt[i]; }
    lofs2[NPB] = run;
  }
  __syncthreads();
  if (threadIdx.x < NPB) {
    int node = lo + threadIdx.x;
    if (node < N) {
      rowptr[node] = e0 + lofs2[threadIdx.x];
      dis[node] = rsqrtf((float)lcnt[threadIdx.x] + 1.0f);  // +1 self loop
    }
    lpos[threadIdx.x] = lofs2[threadIdx.x];
  }
  __syncthreads();
  for (int i = threadIdx.x; i < tot; i += 256) {
    unsigned long long v = bin[(size_t)e0 + i];
    int idx = (int)(v >> 32) & (NPB - 1);
    int p = atomicAdd(&lpos[idx], 1);
    unsigned int s = (unsigned int)v;
    if (p < CAP_B) colbuf[p] = s;
    else col[(size_t)e0 + p] = s;
  }
  __syncthreads();
  int cp = min(tot, CAP_B);
  for (int i = threadIdx.x; i < cp; i += 256)
    __builtin_nontemporal_store(colbuf[i], (unsigned int*)&col[(size_t)e0 + i]);
  if (b == 0 && threadIdx.x == 0) rowptr[N] = E;
}

// ---------------- W pre-pack into MFMA B-fragment order (fp16) ----------------
// B-frag for 16x16x32_f16: lane holds B[k = (lane>>4)*8 + j][n = lane&15].
// Wp flat index: ((ct*(K/32) + ks)*64 + lane)*8 + j, ct = n>>4, ks = k>>5.

template <int K, int N>
__global__ __launch_bounds__(256) void k_packW(const float* __restrict__ W,
                                               _Float16* __restrict__ Wp) {
  int idx = blockIdx.x * 256 + threadIdx.x;
  if (idx >= K * N) return;
  int k = idx / N, n = idx % N;
  int ct = n >> 4, ks = k >> 5, q = (k >> 3) & 3, j = k & 7;
  int lane = (n & 15) + (q << 4);
  Wp[((((size_t)ct * (K / 32) + ks) * 64 + lane) << 3) + j] = (_Float16)W[idx];
}

// ---------------- MFMA GEMM: out = fp16(dis[r] * (A @ W)) in SLICE-MAJOR layout --------
// Output layout: out[slice][row][16] halves, slice = col>>4 (feeds sliced agg).
// A input: fp32 node-major (layer 1) or fp16 slice-major [K/16][M][16] (layers 2,3).

template <int K, int N, typename AT, bool ASL>
__global__ __launch_bounds__(256) void k_gemm_mfma(const AT* __restrict__ A,
                                                   const _Float16* __restrict__ Wp,
                                                   const float* __restrict__ dis,
                                                   __half* __restrict__ out, int M) {
  constexpr int CT = N / 16;   // 16-col tiles (= output slices)
  constexpr int KS = K / 32;   // 32-k steps
  const int wave = threadIdx.x >> 6, lane = threadIdx.x & 63;
  const int q = lane >> 4, mlane = lane & 15;
  const int row0 = blockIdx.x * 64 + wave * 16;
  int arow = row0 + mlane;
  if (arow > M - 1) arow = M - 1;  // clamp (dup row, stores guarded)

  floatx4 acc[CT];
#pragma unroll
  for (int c = 0; c < CT; c++) acc[c] = (floatx4){0.f, 0.f, 0.f, 0.f};

#pragma unroll
  for (int ks = 0; ks < KS; ks++) {
    half8 a;
    if constexpr (sizeof(AT) == 4) {
      const float* ap = &A[(size_t)arow * K + ks * 32 + q * 8];
      float4 f0 = *(const float4*)ap;
      float4 f1 = *(const float4*)(ap + 4);
      a[0] = (_Float16)f0.x; a[1] = (_Float16)f0.y;
      a[2] = (_Float16)f0.z; a[3] = (_Float16)f0.w;
      a[4] = (_Float16)f1.x; a[5] = (_Float16)f1.y;
      a[6] = (_Float16)f1.z; a[7] = (_Float16)f1.w;
    } else if constexpr (ASL) {
      // slice-major A: k = ks*32 + q*8 + j -> slice = 2*ks + (q>>1), off = (q&1)*8
      const int sl = ks * 2 + (q >> 1);
      a = *(const half8*)&A[((size_t)sl * M + arow) * 16 + (q & 1) * 8];
    } else {
      a = *(const half8*)&A[(size_t)arow * K + ks * 32 + q * 8];
    }
#pragma unroll
    for (int c = 0; c < CT; c++) {
      half8 b = *(const half8*)&Wp[((((size_t)c * KS) + ks) * 64 + lane) << 3];
      acc[c] = __builtin_amdgcn_mfma_f32_16x16x32_f16(a, b, acc[c], 0, 0, 0);
    }
  }

  // C/D layout: col = lane&15 (+ct*16), row = q*4 + r ; store slice-major
  float dv[4]; int orow[4];
#pragma unroll
  for (int r = 0; r < 4; r++) {
    orow[r] = row0 + q * 4 + r;
    dv[r] = (orow[r] < M) ? dis[orow[r]] : 0.f;
  }
#pragma unroll
  for (int c = 0; c < CT; c++) {
#pragma unroll
    for (int r = 0; r < 4; r++)
      if (orow[r] < M)
        out[((size_t)c * M + orow[r]) * 16 + mlane] = __float2half_rn(dv[r] * acc[c][r]);
  }
}

// ---------------- sliced aggregation: out[v] = act(dv*(g[v] + sum_u g[u]) + b) -------
// Feature dim split into NS slices of 16; slice s bound to XCD(s) via blockIdx%8 so the
// 3.2 MB slice table stays resident in that XCD's 4 MB L2 -> gathers become L2 hits.
// Wave = 8 subgroups x 8 lanes; subgroup = 1 node; lane = 1 dim-pair (half2).
// NS=8 (F=128): 1 XCD per slice, full node range. NS=4 (F=64): 2 XCDs per slice,
// node range split in half. col/rowptr re-read per slice (streamed, nt loads).

template <int NS, bool RELU, typename OUT_T>
__global__ __launch_bounds__(256) void k_agg_slice(const __half* __restrict__ g,
                                                   const int* __restrict__ rowptr,
                                                   const int* __restrict__ col,
                                                   const float* __restrict__ dis,
                                                   const float* __restrict__ bias,
                                                   OUT_T* __restrict__ out, int n) {
  constexpr int XPS = 8 / NS;            // XCD replicas per slice
  const int lane = threadIdx.x & 63;
  const int sub  = lane >> 3;            // subgroup (node) within wave
  const int li   = lane & 7;             // lane in subgroup (dim pair)
  const int wave = threadIdx.x >> 6;
  const int bx   = blockIdx.x;
  const int xcd  = bx & 7;               // XCD binding (perf heuristic)
  const int s    = xcd / XPS;            // slice id
  const int part = xcd % XPS;            // node-range partition
  const int nper = (n + XPS - 1) / XPS;
  const int v0   = part * nper;
  const int v1   = min(n, v0 + nper);
  const int v    = v0 + ((bx >> 3) * 4 + wave) * 8 + sub;
  if (v >= v1) return;

  const __half2* __restrict__ gs = (const __half2*)g + (size_t)s * n * 8;
  int p = rowptr[v], end = rowptr[v + 1];
  float2 acc = __half22float2(gs[(size_t)v * 8 + li]);  // self term

  int rem = end - p;
  while (rem >= 8) {                     // full chunks: unpredicated
    int u[8]; __half2 t[8];
#pragma unroll
    for (int j = 0; j < 8; j++) u[j] = __builtin_nontemporal_load(&col[p + j]);
#pragma unroll
    for (int j = 0; j < 8; j++) t[j] = gs[(size_t)u[j] * 8 + li];
#pragma unroll
    for (int j = 0; j < 8; j++) {
      float2 f = __half22float2(t[j]);
      acc.x += f.x; acc.y += f.y;
    }
    p += 8; rem -= 8;
  }
  if (rem > 0) {                          // masked tail chunk
    int u[8]; __half2 t[8];
#pragma unroll
    for (int j = 0; j < 8; j++)
      u[j] = __builtin_nontemporal_load(&col[(j < rem) ? p + j : p]);
#pragma unroll
    for (int j = 0; j < 8; j++) t[j] = gs[(size_t)u[j] * 8 + li];
#pragma unroll
    for (int j = 0; j < 8; j++) {
      float2 f = __half22float2(t[j]);
      if (j < rem) { acc.x += f.x; acc.y += f.y; }
    }
  }

  float dv = dis[v];
  float2 bv = *(const float2*)&bias[s * 16 + li * 2];
  float ox = fmaf(dv, acc.x, bv.x);
  float oy = fmaf(dv, acc.y, bv.y);
  if (RELU) { ox = fmaxf(ox, 0.f); oy = fmaxf(oy, 0.f); }
  if constexpr (sizeof(OUT_T) == 2) {
    // fp16 slice-major [NS][n][16] (feeds next sliced GEMM)
    __half2 h = __float22half2_rn(make_float2(ox, oy));
    __builtin_nontemporal_store(*(const unsigned int*)&h,
        (unsigned int*)&out[((size_t)s * n + v) * 16 + li * 2]);
  } else {
    // fp32 node-major [n][NS*16] (final output)
    float2 o = make_float2(ox, oy);
    __builtin_nontemporal_store(*(const unsigned long long*)&o,
        (unsigned long long*)&out[(size_t)v * (NS * 16) + s * 16 + li * 2]);
  }
}

// ---------------- launch ----------------

extern "C" void kernel_launch(void* const* d_in, const int* in_sizes, int n_in,
                              void* d_out, int out_size, void* d_ws, size_t ws_size,
                              hipStream_t stream) {
  const float* x  = (const float*)d_in[0];
  const int*   ei = (const int*)d_in[1];
  const float* W1 = (const float*)d_in[2];
  const float* b1 = (const float*)d_in[3];
  const float* W2 = (const float*)d_in[4];
  const float* b2 = (const float*)d_in[5];
  const float* W3 = (const float*)d_in[6];
  const float* b3 = (const float*)d_in[7];
  float* outp = (float*)d_out;

  const int N = in_sizes[0] / IN_DIM;   // 100000
  const int E = in_sizes[1] / 2;        // 3200000
  const int* src = ei;
  const int* dst = ei + E;
  const int NB = (N + NPB - 1) >> NPB_SHIFT;  // 391 buckets

  char* w = (char*)d_ws;
  auto take = [&](size_t bytes) {
    char* r = w;
    w += (bytes + 255) & ~size_t(255);
    return r;
  };
  float*  dis    = (float*)take((size_t)N * 4);
  int*    rowptr = (int*)take((size_t)(N + 1) * 4);
  int*    bsize  = (int*)take((size_t)NB * 4);
  int*    boff   = (int*)take((size_t)(NB + 1) * 4);
  int*    gcur   = (int*)take((size_t)NB * 4);
  int*    col    = (int*)take((size_t)E * 4);
  unsigned long long* bin = (unsigned long long*)take((size_t)E * 8);
  _Float16* Wp1  = (_Float16*)take((size_t)IN_DIM * HID_DIM * 2);
  _Float16* Wp2  = (_Float16*)take((size_t)HID_DIM * HID_DIM * 2);
  _Float16* Wp3  = (_Float16*)take((size_t)HID_DIM * OUT_DIM * 2);
  __half* gbuf   = (__half*)take((size_t)N * 128 * 2);  // GEMM out (slice-major)
  __half* bufH   = (__half*)take((size_t)N * 128 * 2);  // agg out (slice-major)

  const int cb = (E + CHUNK - 1) / CHUNK;
  hipLaunchKernelGGL(k_zero, dim3((NB + 255) / 256), dim3(256), 0, stream, bsize, NB);
  hipLaunchKernelGGL(k_hist, dim3(cb), dim3(256), 0, stream, dst, E, NB, bsize);
  hipLaunchKernelGGL(k_scanb, dim3(1), dim3(512), 0, stream, bsize, NB, E, boff, gcur);
  hipLaunchKernelGGL(k_binA, dim3(cb), dim3(256), 0, stream, src, dst, E, NB, gcur, bin);
  hipLaunchKernelGGL(k_passB, dim3(NB), dim3(256), 0, stream, bin, boff, NB, N, E, rowptr, dis, col);

  hipLaunchKernelGGL((k_packW<IN_DIM, HID_DIM>), dim3((IN_DIM * HID_DIM + 255) / 256), dim3(256), 0, stream, W1, Wp1);
  hipLaunchKernelGGL((k_packW<HID_DIM, HID_DIM>), dim3((HID_DIM * HID_DIM + 255) / 256), dim3(256), 0, stream, W2, Wp2);
  hipLaunchKernelGGL((k_packW<HID_DIM, OUT_DIM>), dim3((HID_DIM * OUT_DIM + 255) / 256), dim3(256), 0, stream, W3, Wp3);

  const int gb = (N + 63) / 64;
  // agg grids: 8 XCD-bound lanes x enough blocks of 32 nodes for the per-XCD node range
  auto aggGrid = [&](int NSv) {
    int xps = 8 / NSv;
    int nper = (N + xps - 1) / xps;
    return 8 * ((nper + 31) / 32);
  };
  const int ag8 = aggGrid(8);   // F=128 layers
  const int ag4 = aggGrid(4);   // F=64 final layer

  // layer 1: gbuf[slice-major] = fp16(dis*(x@W1)) -> sliced agg+relu -> bufH
  hipLaunchKernelGGL((k_gemm_mfma<IN_DIM, HID_DIM, float, false>), dim3(gb), dim3(256), 0, stream, x, Wp1, dis, gbuf, N);
  hipLaunchKernelGGL((k_agg_slice<8, true, __half>), dim3(ag8), dim3(256), 0, stream, gbuf, rowptr, col, dis, b1, bufH, N);
  // layer 2 (A slice-major)
  hipLaunchKernelGGL((k_gemm_mfma<HID_DIM, HID_DIM, __half, true>), dim3(gb), dim3(256), 0, stream, bufH, Wp2, dis, gbuf, N);
  hipLaunchKernelGGL((k_agg_slice<8, true, __half>), dim3(ag8), dim3(256), 0, stream, gbuf, rowptr, col, dis, b2, bufH, N);
  // layer 3 (no relu), 64-dim, fp32 node-major straight to d_out
  hipLaunchKernelGGL((k_gemm_mfma<HID_DIM, OUT_DIM, __half, true>), dim3(gb), dim3(256), 0, stream, bufH, Wp3, dis, gbuf, N);
  hipLaunchKernelGGL((k_agg_slice<4, false, float>), dim3(ag4), dim3(256), 0, stream, gbuf, rowptr, col, dis, b3, outp, N);
}

// Round 3
// 900.971 us; speedup vs baseline: 1.1053x; 1.1053x over previous
//
#include <hip/hip_runtime.h>
#include <hip/hip_fp16.h>

constexpr int IN_DIM  = 256;
constexpr int HID_DIM = 128;
constexpr int OUT_DIM = 64;

constexpr int NPB_SHIFT = 8;          // 256 nodes per bucket
constexpr int NPB   = 1 << NPB_SHIFT;
constexpr int NBMAX = 512;            // max buckets supported in LDS tables
constexpr int CHUNK = 4096;           // edges per binning block
constexpr int CAP_B = 12288;          // LDS col-stage capacity (48 KB)

typedef _Float16 half8 __attribute__((ext_vector_type(8)));
typedef float floatx4 __attribute__((ext_vector_type(4)));

// ---------------- CSR build via bucketed counting sort ----------------

__global__ __launch_bounds__(256) void k_hist(const int* __restrict__ dst, int E, int NB,
                                              int* __restrict__ bsize) {
  __shared__ int h[NBMAX];
  for (int i = threadIdx.x; i < NB; i += 256) h[i] = 0;
  __syncthreads();
  int e0 = blockIdx.x * CHUNK;
  int e1 = min(e0 + CHUNK, E);
  for (int e = e0 + threadIdx.x; e < e1; e += 256) {
    int d = __builtin_nontemporal_load(&dst[e]);
    atomicAdd(&h[d >> NPB_SHIFT], 1);
  }
  __syncthreads();
  for (int b = threadIdx.x; b < NB; b += 256) {
    int c = h[b];
    if (c) atomicAdd(&bsize[b], c);
  }
}

__global__ __launch_bounds__(512) void k_scanb(const int* __restrict__ bsize, int NB, int E,
                                               int* __restrict__ boff, int* __restrict__ gcur) {
  __shared__ int sh[NBMAX + 1];
  for (int i = threadIdx.x; i < NB; i += 512) sh[i] = bsize[i];
  __syncthreads();
  if (threadIdx.x == 0) {
    int run = 0;
    for (int b = 0; b < NB; b++) { int v = sh[b]; sh[b] = run; run += v; }
    sh[NB] = run;
  }
  __syncthreads();
  for (int i = threadIdx.x; i < NB; i += 512) { boff[i] = sh[i]; gcur[i] = sh[i]; }
  if (threadIdx.x == 0) boff[NB] = sh[NB];
}

// bin entry: 4 bytes = (dst&255)<<24 | src  (src < 2^24; bucket from position)
__global__ __launch_bounds__(256) void k_binA(const int* __restrict__ src,
                                              const int* __restrict__ dst, int E, int NB,
                                              int* __restrict__ gcur,
                                              unsigned int* __restrict__ bin) {
  __shared__ unsigned int sbuf[CHUNK];      // 16 KB
  __shared__ unsigned short sbb[CHUNK];     // 8 KB (bucket per staged entry)
  __shared__ int h[NBMAX], lofs[NBMAX], wofs[NBMAX], hcur[NBMAX];
  for (int i = threadIdx.x; i < NB; i += 256) h[i] = 0;
  __syncthreads();
  int e0 = blockIdx.x * CHUNK;
  int e1 = min(e0 + CHUNK, E);
  for (int e = e0 + threadIdx.x; e < e1; e += 256) {
    int d = __builtin_nontemporal_load(&dst[e]);
    atomicAdd(&h[d >> NPB_SHIFT], 1);
  }
  __syncthreads();
  for (int b = threadIdx.x; b < NB; b += 256) {
    int c = h[b];
    if (c) wofs[b] = atomicAdd(&gcur[b], c);
  }
  if (threadIdx.x == 0) {
    int run = 0;
    for (int b = 0; b < NB; b++) { lofs[b] = run; run += h[b]; }
  }
  __syncthreads();
  for (int b = threadIdx.x; b < NB; b += 256) hcur[b] = lofs[b];
  __syncthreads();
  for (int e = e0 + threadIdx.x; e < e1; e += 256) {
    int d = dst[e];
    int s = src[e];
    int b = d >> NPB_SHIFT;
    int p = atomicAdd(&hcur[b], 1);
    sbuf[p] = ((unsigned int)(d & (NPB - 1)) << 24) | (unsigned int)s;
    sbb[p] = (unsigned short)b;
  }
  __syncthreads();
  int total = e1 - e0;
  for (int i = threadIdx.x; i < total; i += 256) {
    int b = sbb[i];
    bin[(size_t)wofs[b] + (i - lofs[b])] = sbuf[i];
  }
}

__global__ __launch_bounds__(256) void k_passB(const unsigned int* __restrict__ bin,
                                               const int* __restrict__ boff, int NB, int N, int E,
                                               int* __restrict__ rowptr, float* __restrict__ dis,
                                               int* __restrict__ col) {
  __shared__ unsigned int colbuf[CAP_B];  // 48 KB
  __shared__ int lcnt[NPB], lofs2[NPB + 1], lpos[NPB];
  int b = blockIdx.x;
  int lo = b << NPB_SHIFT;
  int e0 = boff[b], e1 = boff[b + 1];
  int tot = e1 - e0;
  if (threadIdx.x < NPB) lcnt[threadIdx.x] = 0;
  __syncthreads();
  for (int i = threadIdx.x; i < tot; i += 256) {
    unsigned int v = bin[(size_t)e0 + i];
    atomicAdd(&lcnt[v >> 24], 1);
  }
  __syncthreads();
  if (threadIdx.x == 0) {
    int run = 0;
    for (int i = 0; i < NPB; i++) { lofs2[i] = run; run += lcnt[i]; }
    lofs2[NPB] = run;
  }
  __syncthreads();
  if (threadIdx.x < NPB) {
    int node = lo + threadIdx.x;
    if (node < N) {
      rowptr[node] = e0 + lofs2[threadIdx.x];
      dis[node] = rsqrtf((float)lcnt[threadIdx.x] + 1.0f);  // +1 self loop
    }
    lpos[threadIdx.x] = lofs2[threadIdx.x];
  }
  __syncthreads();
  for (int i = threadIdx.x; i < tot; i += 256) {
    unsigned int v = bin[(size_t)e0 + i];
    int idx = v >> 24;
    int p = atomicAdd(&lpos[idx], 1);
    unsigned int s = v & 0x00FFFFFFu;
    if (p < CAP_B) colbuf[p] = s;
    else col[(size_t)e0 + p] = (int)s;
  }
  __syncthreads();
  int cp = min(tot, CAP_B);
  for (int i = threadIdx.x; i < cp; i += 256)
    __builtin_nontemporal_store(colbuf[i], (unsigned int*)&col[(size_t)e0 + i]);
  if (b == 0 && threadIdx.x == 0) rowptr[N] = E;
}

// ---------------- W pre-pack into MFMA B-fragment order (fp16) ----------------
// B-frag for 16x16x32_f16: lane holds B[k = (lane>>4)*8 + j][n = lane&15].
// Wp flat index: ((ct*(K/32) + ks)*64 + lane)*8 + j, ct = n>>4, ks = k>>5.

template <int K, int N>
__device__ inline void packW_one(const float* __restrict__ W, _Float16* __restrict__ Wp,
                                 int idx) {
  int k = idx / N, n = idx % N;
  int ct = n >> 4, ks = k >> 5, q = (k >> 3) & 3, j = k & 7;
  int lane = (n & 15) + (q << 4);
  Wp[((((size_t)ct * (K / 32) + ks) * 64 + lane) << 3) + j] = (_Float16)W[idx];
}

__global__ __launch_bounds__(256) void k_packAll(const float* __restrict__ W1, _Float16* __restrict__ Wp1,
                                                 const float* __restrict__ W2, _Float16* __restrict__ Wp2,
                                                 const float* __restrict__ W3, _Float16* __restrict__ Wp3) {
  constexpr int S1 = IN_DIM * HID_DIM;            // 32768
  constexpr int S2 = S1 + HID_DIM * HID_DIM;      // 49152
  constexpr int S3 = S2 + HID_DIM * OUT_DIM;      // 57344
  int idx = blockIdx.x * 256 + threadIdx.x;
  if (idx < S1) packW_one<IN_DIM, HID_DIM>(W1, Wp1, idx);
  else if (idx < S2) packW_one<HID_DIM, HID_DIM>(W2, Wp2, idx - S1);
  else if (idx < S3) packW_one<HID_DIM, OUT_DIM>(W3, Wp3, idx - S2);
}

// ---------------- MFMA GEMM: out[r][c] = fp16(dis[r] * sum_k A[r][k]*W[k][c]) --------
// No LDS. Block = 4 waves; wave w computes rows [blk*64 + w*16, +16) x all N cols.

template <int K, int N, typename AT>
__global__ __launch_bounds__(256) void k_gemm_mfma(const AT* __restrict__ A,
                                                   const _Float16* __restrict__ Wp,
                                                   const float* __restrict__ dis,
                                                   __half* __restrict__ out, int M) {
  constexpr int CT = N / 16;   // 16-col tiles
  constexpr int KS = K / 32;   // 32-k steps
  const int wave = threadIdx.x >> 6, lane = threadIdx.x & 63;
  const int q = lane >> 4, mlane = lane & 15;
  const int row0 = blockIdx.x * 64 + wave * 16;
  int arow = row0 + mlane;
  if (arow > M - 1) arow = M - 1;  // clamp (dup row, stores guarded)

  floatx4 acc[CT];
#pragma unroll
  for (int c = 0; c < CT; c++) acc[c] = (floatx4){0.f, 0.f, 0.f, 0.f};

#pragma unroll
  for (int ks = 0; ks < KS; ks++) {
    half8 a;
    if constexpr (sizeof(AT) == 4) {
      const float* ap = &A[(size_t)arow * K + ks * 32 + q * 8];
      float4 f0 = *(const float4*)ap;
      float4 f1 = *(const float4*)(ap + 4);
      a[0] = (_Float16)f0.x; a[1] = (_Float16)f0.y;
      a[2] = (_Float16)f0.z; a[3] = (_Float16)f0.w;
      a[4] = (_Float16)f1.x; a[5] = (_Float16)f1.y;
      a[6] = (_Float16)f1.z; a[7] = (_Float16)f1.w;
    } else {
      a = *(const half8*)&A[(size_t)arow * K + ks * 32 + q * 8];
    }
#pragma unroll
    for (int c = 0; c < CT; c++) {
      half8 b = *(const half8*)&Wp[((((size_t)c * KS) + ks) * 64 + lane) << 3];
      acc[c] = __builtin_amdgcn_mfma_f32_16x16x32_f16(a, b, acc[c], 0, 0, 0);
    }
  }

  // C/D layout: col = lane&15 (+ct*16), row = q*4 + r
  float dv[4]; int orow[4];
#pragma unroll
  for (int r = 0; r < 4; r++) {
    orow[r] = row0 + q * 4 + r;
    dv[r] = (orow[r] < M) ? dis[orow[r]] : 0.f;
  }
#pragma unroll
  for (int c = 0; c < CT; c++) {
    int cl = c * 16 + mlane;
#pragma unroll
    for (int r = 0; r < 4; r++)
      if (orow[r] < M)
        out[(size_t)orow[r] * N + cl] = __float2half_rn(dv[r] * acc[c][r]);
  }
}

// ---------------- aggregation (half-feature pass): 64 dims of a 128-dim table -------
// out[v][hh*64+lane] = relu(dv*(g[v]+sum_u g[u]) + b). One wave per node; lane = one
// dim (2B scalar gather, 2 lines per edge-row — v0's proven F=64 pattern). Each pass
// touches only 12.8 MB of the 25.6 MB table -> better per-XCD L2 retention; passes
// are independent and launched back-to-back (hh = 0, 1).

template <bool RELU>
__global__ __launch_bounds__(256) void k_aggH(const __half* __restrict__ g,
                                              const int* __restrict__ rowptr,
                                              const int* __restrict__ col,
                                              const float* __restrict__ dis,
                                              const float* __restrict__ bias,
                                              __half* __restrict__ out, int n, int hh) {
  const int lane = threadIdx.x & 63;
  const int v = blockIdx.x * 4 + (threadIdx.x >> 6);
  if (v >= n) return;
  int p = rowptr[v], end = rowptr[v + 1];
  const float dv = dis[v];
  const __half* __restrict__ gh = g + hh * 64;  // column offset into [N][128]

  float acc = __half2float(gh[(size_t)v * 128 + lane]);  // self term
  for (; p + 8 <= end; p += 8) {
    int u[8];
#pragma unroll
    for (int j = 0; j < 8; j++) u[j] = __builtin_nontemporal_load(&col[p + j]);
    __half t[8];
#pragma unroll
    for (int j = 0; j < 8; j++) t[j] = gh[(size_t)u[j] * 128 + lane];
#pragma unroll
    for (int j = 0; j < 8; j++) acc += __half2float(t[j]);
  }
  for (; p < end; p++) {
    int u = __builtin_nontemporal_load(&col[p]);
    acc += __half2float(gh[(size_t)u * 128 + lane]);
  }
  float o = fmaf(dv, acc, bias[hh * 64 + lane]);
  if (RELU) o = fmaxf(o, 0.f);
  out[(size_t)v * 128 + hh * 64 + lane] = __float2half_rn(o);
}

// ---------------- final-layer aggregation: F=64, fp32 out, no relu (v0-proven) ------

__global__ __launch_bounds__(256) void k_agg64(const __half* __restrict__ g,
                                               const int* __restrict__ rowptr,
                                               const int* __restrict__ col,
                                               const float* __restrict__ dis,
                                               const float* __restrict__ bias,
                                               float* __restrict__ out, int n) {
  const int lane = threadIdx.x & 63;
  const int v = blockIdx.x * 4 + (threadIdx.x >> 6);
  if (v >= n) return;
  int p = rowptr[v], end = rowptr[v + 1];
  const float dv = dis[v];

  float acc = __half2float(g[(size_t)v * 64 + lane]);
  for (; p + 8 <= end; p += 8) {
    int u[8];
#pragma unroll
    for (int j = 0; j < 8; j++) u[j] = __builtin_nontemporal_load(&col[p + j]);
    __half t[8];
#pragma unroll
    for (int j = 0; j < 8; j++) t[j] = g[(size_t)u[j] * 64 + lane];
#pragma unroll
    for (int j = 0; j < 8; j++) acc += __half2float(t[j]);
  }
  for (; p < end; p++) {
    int u = __builtin_nontemporal_load(&col[p]);
    acc += __half2float(g[(size_t)u * 64 + lane]);
  }
  float o = fmaf(dv, acc, bias[lane]);
  out[(size_t)v * 64 + lane] = o;
}

// ---------------- launch ----------------

extern "C" void kernel_launch(void* const* d_in, const int* in_sizes, int n_in,
                              void* d_out, int out_size, void* d_ws, size_t ws_size,
                              hipStream_t stream) {
  const float* x  = (const float*)d_in[0];
  const int*   ei = (const int*)d_in[1];
  const float* W1 = (const float*)d_in[2];
  const float* b1 = (const float*)d_in[3];
  const float* W2 = (const float*)d_in[4];
  const float* b2 = (const float*)d_in[5];
  const float* W3 = (const float*)d_in[6];
  const float* b3 = (const float*)d_in[7];
  float* outp = (float*)d_out;

  const int N = in_sizes[0] / IN_DIM;   // 100000
  const int E = in_sizes[1] / 2;        // 3200000
  const int* src = ei;
  const int* dst = ei + E;
  const int NB = (N + NPB - 1) >> NPB_SHIFT;  // 391 buckets

  char* w = (char*)d_ws;
  auto take = [&](size_t bytes) {
    char* r = w;
    w += (bytes + 255) & ~size_t(255);
    return r;
  };
  float*  dis    = (float*)take((size_t)N * 4);
  int*    rowptr = (int*)take((size_t)(N + 1) * 4);
  int*    bsize  = (int*)take((size_t)NB * 4);
  int*    boff   = (int*)take((size_t)(NB + 1) * 4);
  int*    gcur   = (int*)take((size_t)NB * 4);
  int*    col    = (int*)take((size_t)E * 4);
  unsigned int* bin = (unsigned int*)take((size_t)E * 4);
  _Float16* Wp1  = (_Float16*)take((size_t)IN_DIM * HID_DIM * 2);
  _Float16* Wp2  = (_Float16*)take((size_t)HID_DIM * HID_DIM * 2);
  _Float16* Wp3  = (_Float16*)take((size_t)HID_DIM * OUT_DIM * 2);
  __half* gbuf   = (__half*)take((size_t)N * 128 * 2);  // GEMM out / gather buffer
  __half* bufH   = (__half*)take((size_t)N * 128 * 2);  // agg out (next GEMM A)

  const int cb = (E + CHUNK - 1) / CHUNK;
  hipMemsetAsync(bsize, 0, (size_t)NB * 4, stream);
  hipLaunchKernelGGL(k_hist, dim3(cb), dim3(256), 0, stream, dst, E, NB, bsize);
  hipLaunchKernelGGL(k_scanb, dim3(1), dim3(512), 0, stream, bsize, NB, E, boff, gcur);
  hipLaunchKernelGGL(k_binA, dim3(cb), dim3(256), 0, stream, src, dst, E, NB, gcur, bin);
  hipLaunchKernelGGL(k_passB, dim3(NB), dim3(256), 0, stream, bin, boff, NB, N, E, rowptr, dis, col);

  hipLaunchKernelGGL(k_packAll, dim3((IN_DIM * HID_DIM + HID_DIM * HID_DIM + HID_DIM * OUT_DIM + 255) / 256),
                     dim3(256), 0, stream, W1, Wp1, W2, Wp2, W3, Wp3);

  const int gb = (N + 63) / 64;
  const int ab = (N + 3) / 4;
  // layer 1: gbuf = fp16(dis*(x@W1)) -> agg+relu (two half passes) -> bufH (fp16)
  hipLaunchKernelGGL((k_gemm_mfma<IN_DIM, HID_DIM, float>), dim3(gb), dim3(256), 0, stream, x, Wp1, dis, gbuf, N);
  hipLaunchKernelGGL((k_aggH<true>), dim3(ab), dim3(256), 0, stream, gbuf, rowptr, col, dis, b1, bufH, N, 0);
  hipLaunchKernelGGL((k_aggH<true>), dim3(ab), dim3(256), 0, stream, gbuf, rowptr, col, dis, b1, bufH, N, 1);
  // layer 2
  hipLaunchKernelGGL((k_gemm_mfma<HID_DIM, HID_DIM, __half>), dim3(gb), dim3(256), 0, stream, bufH, Wp2, dis, gbuf, N);
  hipLaunchKernelGGL((k_aggH<true>), dim3(ab), dim3(256), 0, stream, gbuf, rowptr, col, dis, b2, bufH, N, 0);
  hipLaunchKernelGGL((k_aggH<true>), dim3(ab), dim3(256), 0, stream, gbuf, rowptr, col, dis, b2, bufH, N, 1);
  // layer 3 (no relu), 64-dim, fp32 straight to d_out
  hipLaunchKernelGGL((k_gemm_mfma<HID_DIM, OUT_DIM, __half>), dim3(gb), dim3(256), 0, stream, bufH, Wp3, dis, gbuf, N);
  hipLaunchKernelGGL(k_agg64, dim3(ab), dim3(256), 0, stream, gbuf, rowptr, col, dis, b3, outp, N);
}

// Round 4
// 623.265 us; speedup vs baseline: 1.5978x; 1.4456x over previous
//
#include <hip/hip_runtime.h>
#include <hip/hip_fp16.h>

constexpr int IN_DIM  = 256;
constexpr int HID_DIM = 128;
constexpr int OUT_DIM = 64;

constexpr int NPB_SHIFT = 8;          // 256 nodes per bucket
constexpr int NPB   = 1 << NPB_SHIFT;
constexpr int NBMAX = 512;            // max buckets supported in LDS tables
constexpr int CHUNK = 4096;           // edges per binning block
constexpr int CAP_B = 12288;          // LDS col-stage capacity (48 KB)

typedef _Float16 half8 __attribute__((ext_vector_type(8)));
typedef float floatx4 __attribute__((ext_vector_type(4)));

// ---------------- CSR build via bucketed counting sort ----------------

__global__ __launch_bounds__(256) void k_hist(const int* __restrict__ dst, int E, int NB,
                                              int* __restrict__ bsize) {
  __shared__ int h[NBMAX];
  for (int i = threadIdx.x; i < NB; i += 256) h[i] = 0;
  __syncthreads();
  int e0 = blockIdx.x * CHUNK;
  int e1 = min(e0 + CHUNK, E);
  for (int e = e0 + threadIdx.x; e < e1; e += 256) {
    int d = __builtin_nontemporal_load(&dst[e]);
    atomicAdd(&h[d >> NPB_SHIFT], 1);
  }
  __syncthreads();
  for (int b = threadIdx.x; b < NB; b += 256) {
    int c = h[b];
    if (c) atomicAdd(&bsize[b], c);
  }
}

__global__ __launch_bounds__(512) void k_scanb(const int* __restrict__ bsize, int NB, int E,
                                               int* __restrict__ boff, int* __restrict__ gcur) {
  __shared__ int sh[NBMAX + 1];
  for (int i = threadIdx.x; i < NB; i += 512) sh[i] = bsize[i];
  __syncthreads();
  if (threadIdx.x == 0) {
    int run = 0;
    for (int b = 0; b < NB; b++) { int v = sh[b]; sh[b] = run; run += v; }
    sh[NB] = run;
  }
  __syncthreads();
  for (int i = threadIdx.x; i < NB; i += 512) { boff[i] = sh[i]; gcur[i] = sh[i]; }
  if (threadIdx.x == 0) boff[NB] = sh[NB];
}

// bin entry: 4 bytes = (dst&255)<<24 | src  (src < 2^24; bucket from position)
__global__ __launch_bounds__(256) void k_binA(const int* __restrict__ src,
                                              const int* __restrict__ dst, int E, int NB,
                                              int* __restrict__ gcur,
                                              unsigned int* __restrict__ bin) {
  __shared__ unsigned int sbuf[CHUNK];      // 16 KB
  __shared__ unsigned short sbb[CHUNK];     // 8 KB (bucket per staged entry)
  __shared__ int h[NBMAX], lofs[NBMAX], wofs[NBMAX], hcur[NBMAX];
  for (int i = threadIdx.x; i < NB; i += 256) h[i] = 0;
  __syncthreads();
  int e0 = blockIdx.x * CHUNK;
  int e1 = min(e0 + CHUNK, E);
  for (int e = e0 + threadIdx.x; e < e1; e += 256) {
    int d = __builtin_nontemporal_load(&dst[e]);
    atomicAdd(&h[d >> NPB_SHIFT], 1);
  }
  __syncthreads();
  for (int b = threadIdx.x; b < NB; b += 256) {
    int c = h[b];
    if (c) wofs[b] = atomicAdd(&gcur[b], c);
  }
  if (threadIdx.x == 0) {
    int run = 0;
    for (int b = 0; b < NB; b++) { lofs[b] = run; run += h[b]; }
  }
  __syncthreads();
  for (int b = threadIdx.x; b < NB; b += 256) hcur[b] = lofs[b];
  __syncthreads();
  for (int e = e0 + threadIdx.x; e < e1; e += 256) {
    int d = dst[e];
    int s = src[e];
    int b = d >> NPB_SHIFT;
    int p = atomicAdd(&hcur[b], 1);
    sbuf[p] = ((unsigned int)(d & (NPB - 1)) << 24) | (unsigned int)s;
    sbb[p] = (unsigned short)b;
  }
  __syncthreads();
  int total = e1 - e0;
  for (int i = threadIdx.x; i < total; i += 256) {
    int b = sbb[i];
    bin[(size_t)wofs[b] + (i - lofs[b])] = sbuf[i];
  }
}

__global__ __launch_bounds__(256) void k_passB(const unsigned int* __restrict__ bin,
                                               const int* __restrict__ boff, int NB, int N, int E,
                                               int* __restrict__ rowptr, float* __restrict__ dis,
                                               int* __restrict__ col) {
  __shared__ unsigned int colbuf[CAP_B];  // 48 KB
  __shared__ int lcnt[NPB], lofs2[NPB + 1], lpos[NPB];
  int b = blockIdx.x;
  int lo = b << NPB_SHIFT;
  int e0 = boff[b], e1 = boff[b + 1];
  int tot = e1 - e0;
  if (threadIdx.x < NPB) lcnt[threadIdx.x] = 0;
  __syncthreads();
  for (int i = threadIdx.x; i < tot; i += 256) {
    unsigned int v = bin[(size_t)e0 + i];
    atomicAdd(&lcnt[v >> 24], 1);
  }
  __syncthreads();
  if (threadIdx.x == 0) {
    int run = 0;
    for (int i = 0; i < NPB; i++) { lofs2[i] = run; run += lcnt[i]; }
    lofs2[NPB] = run;
  }
  __syncthreads();
  if (threadIdx.x < NPB) {
    int node = lo + threadIdx.x;
    if (node < N) {
      rowptr[node] = e0 + lofs2[threadIdx.x];
      dis[node] = rsqrtf((float)lcnt[threadIdx.x] + 1.0f);  // +1 self loop
    }
    lpos[threadIdx.x] = lofs2[threadIdx.x];
  }
  __syncthreads();
  for (int i = threadIdx.x; i < tot; i += 256) {
    unsigned int v = bin[(size_t)e0 + i];
    int idx = v >> 24;
    int p = atomicAdd(&lpos[idx], 1);
    unsigned int s = v & 0x00FFFFFFu;
    if (p < CAP_B) colbuf[p] = s;
    else col[(size_t)e0 + p] = (int)s;
  }
  __syncthreads();
  int cp = min(tot, CAP_B);
  for (int i = threadIdx.x; i < cp; i += 256)
    __builtin_nontemporal_store(colbuf[i], (unsigned int*)&col[(size_t)e0 + i]);
  if (b == 0 && threadIdx.x == 0) rowptr[N] = E;
}

// ---------------- W pre-pack into MFMA B-fragment order (fp16) ----------------
// B-frag for 16x16x32_f16: lane holds B[k = (lane>>4)*8 + j][n = lane&15].
// Wp flat index: ((ct*(K/32) + ks)*64 + lane)*8 + j, ct = n>>4, ks = k>>5.

template <int K, int N>
__device__ inline void packW_one(const float* __restrict__ W, _Float16* __restrict__ Wp,
                                 int idx) {
  int k = idx / N, n = idx % N;
  int ct = n >> 4, ks = k >> 5, q = (k >> 3) & 3, j = k & 7;
  int lane = (n & 15) + (q << 4);
  Wp[((((size_t)ct * (K / 32) + ks) * 64 + lane) << 3) + j] = (_Float16)W[idx];
}

__global__ __launch_bounds__(256) void k_packAll(const float* __restrict__ W1, _Float16* __restrict__ Wp1,
                                                 const float* __restrict__ W2, _Float16* __restrict__ Wp2,
                                                 const float* __restrict__ W3, _Float16* __restrict__ Wp3) {
  constexpr int S1 = IN_DIM * HID_DIM;            // 32768
  constexpr int S2 = S1 + HID_DIM * HID_DIM;      // 49152
  constexpr int S3 = S2 + HID_DIM * OUT_DIM;      // 57344
  int idx = blockIdx.x * 256 + threadIdx.x;
  if (idx < S1) packW_one<IN_DIM, HID_DIM>(W1, Wp1, idx);
  else if (idx < S2) packW_one<HID_DIM, HID_DIM>(W2, Wp2, idx - S1);
  else if (idx < S3) packW_one<HID_DIM, OUT_DIM>(W3, Wp3, idx - S2);
}

// ---------------- MFMA GEMM: out[r][c] = fp16(dis[r] * sum_k A[r][k]*W[k][c]) --------
// No LDS. Block = 4 waves; wave w computes rows [blk*64 + w*16, +16) x all N cols.

template <int K, int N, typename AT>
__global__ __launch_bounds__(256) void k_gemm_mfma(const AT* __restrict__ A,
                                                   const _Float16* __restrict__ Wp,
                                                   const float* __restrict__ dis,
                                                   __half* __restrict__ out, int M) {
  constexpr int CT = N / 16;   // 16-col tiles
  constexpr int KS = K / 32;   // 32-k steps
  const int wave = threadIdx.x >> 6, lane = threadIdx.x & 63;
  const int q = lane >> 4, mlane = lane & 15;
  const int row0 = blockIdx.x * 64 + wave * 16;
  int arow = row0 + mlane;
  if (arow > M - 1) arow = M - 1;  // clamp (dup row, stores guarded)

  floatx4 acc[CT];
#pragma unroll
  for (int c = 0; c < CT; c++) acc[c] = (floatx4){0.f, 0.f, 0.f, 0.f};

#pragma unroll
  for (int ks = 0; ks < KS; ks++) {
    half8 a;
    if constexpr (sizeof(AT) == 4) {
      const float* ap = &A[(size_t)arow * K + ks * 32 + q * 8];
      float4 f0 = *(const float4*)ap;
      float4 f1 = *(const float4*)(ap + 4);
      a[0] = (_Float16)f0.x; a[1] = (_Float16)f0.y;
      a[2] = (_Float16)f0.z; a[3] = (_Float16)f0.w;
      a[4] = (_Float16)f1.x; a[5] = (_Float16)f1.y;
      a[6] = (_Float16)f1.z; a[7] = (_Float16)f1.w;
    } else {
      a = *(const half8*)&A[(size_t)arow * K + ks * 32 + q * 8];
    }
#pragma unroll
    for (int c = 0; c < CT; c++) {
      half8 b = *(const half8*)&Wp[((((size_t)c * KS) + ks) * 64 + lane) << 3];
      acc[c] = __builtin_amdgcn_mfma_f32_16x16x32_f16(a, b, acc[c], 0, 0, 0);
    }
  }

  // C/D layout: col = lane&15 (+ct*16), row = q*4 + r
  float dv[4]; int orow[4];
#pragma unroll
  for (int r = 0; r < 4; r++) {
    orow[r] = row0 + q * 4 + r;
    dv[r] = (orow[r] < M) ? dis[orow[r]] : 0.f;
  }
#pragma unroll
  for (int c = 0; c < CT; c++) {
    int cl = c * 16 + mlane;
#pragma unroll
    for (int r = 0; r < 4; r++)
      if (orow[r] < M)
        out[(size_t)orow[r] * N + cl] = __float2half_rn(dv[r] * acc[c][r]);
  }
}

// ---------------- aggregation F=128, quad-gather ----------------
// One wave per node. Lane = (r,c): r = lane>>4 (neighbor-in-quad), c = lane&15
// (16B chunk of the 256 B row). One gather instruction fetches FOUR neighbor
// rows (16 lanes x half8 each) -> 4x fewer divergent gather instructions,
// which round-3 data showed is the binding cost (~fixed cost per wave-gather).
// Per-lane fp32 partial sums over dims [c*8, c*8+8); cross-lane shfl_xor(16,32)
// merges the 4 row-groups at the end; r==0 lanes apply bias/relu and store 16 B.

template <bool RELU>
__global__ __launch_bounds__(256) void k_agg128(const __half* __restrict__ g,
                                                const int* __restrict__ rowptr,
                                                const int* __restrict__ col,
                                                const float* __restrict__ dis,
                                                const float* __restrict__ bias,
                                                __half* __restrict__ out, int n) {
  const int lane = threadIdx.x & 63;
  const int r = lane >> 4;          // 0..3
  const int c = lane & 15;          // 0..15
  const int v = blockIdx.x * 4 + (threadIdx.x >> 6);
  if (v >= n) return;
  int p = rowptr[v], end = rowptr[v + 1];
  const float dv = dis[v];

  float acc[8];
#pragma unroll
  for (int i = 0; i < 8; i++) acc[i] = 0.f;
  if (r == 0) {  // self term, counted once
    half8 s = *(const half8*)&g[(size_t)v * 128 + c * 8];
#pragma unroll
    for (int i = 0; i < 8; i++) acc[i] += (float)s[i];
  }

  int rem = end - p;
  while (rem >= 8) {  // two quad-gathers in flight
    int u0 = __builtin_nontemporal_load(&col[p + r]);
    int u1 = __builtin_nontemporal_load(&col[p + 4 + r]);
    half8 t0 = *(const half8*)&g[(size_t)u0 * 128 + c * 8];
    half8 t1 = *(const half8*)&g[(size_t)u1 * 128 + c * 8];
#pragma unroll
    for (int i = 0; i < 8; i++) acc[i] += (float)t0[i];
#pragma unroll
    for (int i = 0; i < 8; i++) acc[i] += (float)t1[i];
    p += 8; rem -= 8;
  }
  if (rem >= 4) {
    int u0 = __builtin_nontemporal_load(&col[p + r]);
    half8 t0 = *(const half8*)&g[(size_t)u0 * 128 + c * 8];
#pragma unroll
    for (int i = 0; i < 8; i++) acc[i] += (float)t0[i];
    p += 4; rem -= 4;
  }
  if (rem > 0) {  // masked tail quad
    int rr = (r < rem) ? r : 0;
    int u0 = __builtin_nontemporal_load(&col[p + rr]);
    half8 t0 = *(const half8*)&g[(size_t)u0 * 128 + c * 8];
    float m = (r < rem) ? 1.f : 0.f;
#pragma unroll
    for (int i = 0; i < 8; i++) acc[i] = fmaf(m, (float)t0[i], acc[i]);
  }

  // merge the 4 row-groups (lanes c, c+16, c+32, c+48)
#pragma unroll
  for (int i = 0; i < 8; i++) {
    acc[i] += __shfl_xor(acc[i], 16);
    acc[i] += __shfl_xor(acc[i], 32);
  }

  if (r == 0) {
    half8 h;
#pragma unroll
    for (int i = 0; i < 8; i++) {
      float o = fmaf(dv, acc[i], bias[c * 8 + i]);
      if (RELU) o = fmaxf(o, 0.f);
      h[i] = (_Float16)o;
    }
    *(half8*)&out[(size_t)v * 128 + c * 8] = h;
  }
}

// ---------------- aggregation F=64, oct-gather, fp32 out, no relu ----------------
// Same idea: r = lane>>3 (neighbor-in-oct), c = lane&7; one gather = 8 rows.

__global__ __launch_bounds__(256) void k_agg64(const __half* __restrict__ g,
                                               const int* __restrict__ rowptr,
                                               const int* __restrict__ col,
                                               const float* __restrict__ dis,
                                               const float* __restrict__ bias,
                                               float* __restrict__ out, int n) {
  const int lane = threadIdx.x & 63;
  const int r = lane >> 3;          // 0..7
  const int c = lane & 7;           // 0..7
  const int v = blockIdx.x * 4 + (threadIdx.x >> 6);
  if (v >= n) return;
  int p = rowptr[v], end = rowptr[v + 1];
  const float dv = dis[v];

  float acc[8];
#pragma unroll
  for (int i = 0; i < 8; i++) acc[i] = 0.f;
  if (r == 0) {
    half8 s = *(const half8*)&g[(size_t)v * 64 + c * 8];
#pragma unroll
    for (int i = 0; i < 8; i++) acc[i] += (float)s[i];
  }

  int rem = end - p;
  while (rem >= 16) {  // two oct-gathers in flight
    int u0 = __builtin_nontemporal_load(&col[p + r]);
    int u1 = __builtin_nontemporal_load(&col[p + 8 + r]);
    half8 t0 = *(const half8*)&g[(size_t)u0 * 64 + c * 8];
    half8 t1 = *(const half8*)&g[(size_t)u1 * 64 + c * 8];
#pragma unroll
    for (int i = 0; i < 8; i++) acc[i] += (float)t0[i];
#pragma unroll
    for (int i = 0; i < 8; i++) acc[i] += (float)t1[i];
    p += 16; rem -= 16;
  }
  if (rem >= 8) {
    int u0 = __builtin_nontemporal_load(&col[p + r]);
    half8 t0 = *(const half8*)&g[(size_t)u0 * 64 + c * 8];
#pragma unroll
    for (int i = 0; i < 8; i++) acc[i] += (float)t0[i];
    p += 8; rem -= 8;
  }
  if (rem > 0) {  // masked tail oct
    int rr = (r < rem) ? r : 0;
    int u0 = __builtin_nontemporal_load(&col[p + rr]);
    half8 t0 = *(const half8*)&g[(size_t)u0 * 64 + c * 8];
    float m = (r < rem) ? 1.f : 0.f;
#pragma unroll
    for (int i = 0; i < 8; i++) acc[i] = fmaf(m, (float)t0[i], acc[i]);
  }

  // merge the 8 row-groups (lanes differing in bits 3..5)
#pragma unroll
  for (int i = 0; i < 8; i++) {
    acc[i] += __shfl_xor(acc[i], 8);
    acc[i] += __shfl_xor(acc[i], 16);
    acc[i] += __shfl_xor(acc[i], 32);
  }

  if (r == 0) {
    float4 o0, o1;
    float ov[8];
#pragma unroll
    for (int i = 0; i < 8; i++) ov[i] = fmaf(dv, acc[i], bias[c * 8 + i]);
    o0.x = ov[0]; o0.y = ov[1]; o0.z = ov[2]; o0.w = ov[3];
    o1.x = ov[4]; o1.y = ov[5]; o1.z = ov[6]; o1.w = ov[7];
    *(float4*)&out[(size_t)v * 64 + c * 8]     = o0;
    *(float4*)&out[(size_t)v * 64 + c * 8 + 4] = o1;
  }
}

// ---------------- launch ----------------

extern "C" void kernel_launch(void* const* d_in, const int* in_sizes, int n_in,
                              void* d_out, int out_size, void* d_ws, size_t ws_size,
                              hipStream_t stream) {
  const float* x  = (const float*)d_in[0];
  const int*   ei = (const int*)d_in[1];
  const float* W1 = (const float*)d_in[2];
  const float* b1 = (const float*)d_in[3];
  const float* W2 = (const float*)d_in[4];
  const float* b2 = (const float*)d_in[5];
  const float* W3 = (const float*)d_in[6];
  const float* b3 = (const float*)d_in[7];
  float* outp = (float*)d_out;

  const int N = in_sizes[0] / IN_DIM;   // 100000
  const int E = in_sizes[1] / 2;        // 3200000
  const int* src = ei;
  const int* dst = ei + E;
  const int NB = (N + NPB - 1) >> NPB_SHIFT;  // 391 buckets

  char* w = (char*)d_ws;
  auto take = [&](size_t bytes) {
    char* r = w;
    w += (bytes + 255) & ~size_t(255);
    return r;
  };
  float*  dis    = (float*)take((size_t)N * 4);
  int*    rowptr = (int*)take((size_t)(N + 1) * 4);
  int*    bsize  = (int*)take((size_t)NB * 4);
  int*    boff   = (int*)take((size_t)(NB + 1) * 4);
  int*    gcur   = (int*)take((size_t)NB * 4);
  int*    col    = (int*)take((size_t)E * 4);
  unsigned int* bin = (unsigned int*)take((size_t)E * 4);
  _Float16* Wp1  = (_Float16*)take((size_t)IN_DIM * HID_DIM * 2);
  _Float16* Wp2  = (_Float16*)take((size_t)HID_DIM * HID_DIM * 2);
  _Float16* Wp3  = (_Float16*)take((size_t)HID_DIM * OUT_DIM * 2);
  __half* gbuf   = (__half*)take((size_t)N * 128 * 2);  // GEMM out / gather buffer
  __half* bufH   = (__half*)take((size_t)N * 128 * 2);  // agg out (next GEMM A)

  const int cb = (E + CHUNK - 1) / CHUNK;
  hipMemsetAsync(bsize, 0, (size_t)NB * 4, stream);
  hipLaunchKernelGGL(k_hist, dim3(cb), dim3(256), 0, stream, dst, E, NB, bsize);
  hipLaunchKernelGGL(k_scanb, dim3(1), dim3(512), 0, stream, bsize, NB, E, boff, gcur);
  hipLaunchKernelGGL(k_binA, dim3(cb), dim3(256), 0, stream, src, dst, E, NB, gcur, bin);
  hipLaunchKernelGGL(k_passB, dim3(NB), dim3(256), 0, stream, bin, boff, NB, N, E, rowptr, dis, col);

  hipLaunchKernelGGL(k_packAll, dim3((IN_DIM * HID_DIM + HID_DIM * HID_DIM + HID_DIM * OUT_DIM + 255) / 256),
                     dim3(256), 0, stream, W1, Wp1, W2, Wp2, W3, Wp3);

  const int gb = (N + 63) / 64;
  const int ab = (N + 3) / 4;
  // layer 1: gbuf = fp16(dis*(x@W1)) -> agg+relu -> bufH (fp16)
  hipLaunchKernelGGL((k_gemm_mfma<IN_DIM, HID_DIM, float>), dim3(gb), dim3(256), 0, stream, x, Wp1, dis, gbuf, N);
  hipLaunchKernelGGL((k_agg128<true>), dim3(ab), dim3(256), 0, stream, gbuf, rowptr, col, dis, b1, bufH, N);
  // layer 2
  hipLaunchKernelGGL((k_gemm_mfma<HID_DIM, HID_DIM, __half>), dim3(gb), dim3(256), 0, stream, bufH, Wp2, dis, gbuf, N);
  hipLaunchKernelGGL((k_agg128<true>), dim3(ab), dim3(256), 0, stream, gbuf, rowptr, col, dis, b2, bufH, N);
  // layer 3 (no relu), 64-dim, fp32 straight to d_out
  hipLaunchKernelGGL((k_gemm_mfma<HID_DIM, OUT_DIM, __half>), dim3(gb), dim3(256), 0, stream, bufH, Wp3, dis, gbuf, N);
  hipLaunchKernelGGL(k_agg64, dim3(ab), dim3(256), 0, stream, gbuf, rowptr, col, dis, b3, outp, N);
}

// Round 5
// 614.329 us; speedup vs baseline: 1.6211x; 1.0145x over previous
//
#include <hip/hip_runtime.h>
#include <hip/hip_fp16.h>

constexpr int IN_DIM  = 256;
constexpr int HID_DIM = 128;
constexpr int OUT_DIM = 64;

constexpr int NPB_SHIFT = 8;          // 256 nodes per bucket
constexpr int NPB   = 1 << NPB_SHIFT;
constexpr int NBMAX = 512;            // max buckets supported in LDS tables
constexpr int CHUNK = 4096;           // edges per binning block
constexpr int CAP_B = 12288;          // LDS col-stage capacity (48 KB)

typedef _Float16 half8 __attribute__((ext_vector_type(8)));
typedef float floatx4 __attribute__((ext_vector_type(4)));

// ---------------- CSR build via bucketed counting sort ----------------

__global__ __launch_bounds__(256) void k_hist(const int* __restrict__ dst, int E, int NB,
                                              int* __restrict__ bsize) {
  __shared__ int h[NBMAX];
  for (int i = threadIdx.x; i < NB; i += 256) h[i] = 0;
  __syncthreads();
  int e0 = blockIdx.x * CHUNK;
  int e1 = min(e0 + CHUNK, E);
  for (int e = e0 + threadIdx.x; e < e1; e += 256) {
    int d = __builtin_nontemporal_load(&dst[e]);
    atomicAdd(&h[d >> NPB_SHIFT], 1);
  }
  __syncthreads();
  for (int b = threadIdx.x; b < NB; b += 256) {
    int c = h[b];
    if (c) atomicAdd(&bsize[b], c);
  }
}

__global__ __launch_bounds__(512) void k_scanb(const int* __restrict__ bsize, int NB, int E,
                                               int* __restrict__ boff, int* __restrict__ gcur) {
  __shared__ int sh[NBMAX + 1];
  for (int i = threadIdx.x; i < NB; i += 512) sh[i] = bsize[i];
  __syncthreads();
  if (threadIdx.x == 0) {
    int run = 0;
    for (int b = 0; b < NB; b++) { int v = sh[b]; sh[b] = run; run += v; }
    sh[NB] = run;
  }
  __syncthreads();
  for (int i = threadIdx.x; i < NB; i += 512) { boff[i] = sh[i]; gcur[i] = sh[i]; }
  if (threadIdx.x == 0) boff[NB] = sh[NB];
}

// bin entry: 4 bytes = (dst&255)<<24 | src  (src < 2^24; bucket from position)
__global__ __launch_bounds__(256) void k_binA(const int* __restrict__ src,
                                              const int* __restrict__ dst, int E, int NB,
                                              int* __restrict__ gcur,
                                              unsigned int* __restrict__ bin) {
  __shared__ unsigned int sbuf[CHUNK];      // 16 KB
  __shared__ unsigned short sbb[CHUNK];     // 8 KB (bucket per staged entry)
  __shared__ int h[NBMAX], lofs[NBMAX], wofs[NBMAX], hcur[NBMAX];
  for (int i = threadIdx.x; i < NB; i += 256) h[i] = 0;
  __syncthreads();
  int e0 = blockIdx.x * CHUNK;
  int e1 = min(e0 + CHUNK, E);
  for (int e = e0 + threadIdx.x; e < e1; e += 256) {
    int d = __builtin_nontemporal_load(&dst[e]);
    atomicAdd(&h[d >> NPB_SHIFT], 1);
  }
  __syncthreads();
  for (int b = threadIdx.x; b < NB; b += 256) {
    int c = h[b];
    if (c) wofs[b] = atomicAdd(&gcur[b], c);
  }
  if (threadIdx.x == 0) {
    int run = 0;
    for (int b = 0; b < NB; b++) { lofs[b] = run; run += h[b]; }
  }
  __syncthreads();
  for (int b = threadIdx.x; b < NB; b += 256) hcur[b] = lofs[b];
  __syncthreads();
  for (int e = e0 + threadIdx.x; e < e1; e += 256) {
    int d = dst[e];
    int s = src[e];
    int b = d >> NPB_SHIFT;
    int p = atomicAdd(&hcur[b], 1);
    sbuf[p] = ((unsigned int)(d & (NPB - 1)) << 24) | (unsigned int)s;
    sbb[p] = (unsigned short)b;
  }
  __syncthreads();
  int total = e1 - e0;
  for (int i = threadIdx.x; i < total; i += 256) {
    int b = sbb[i];
    bin[(size_t)wofs[b] + (i - lofs[b])] = sbuf[i];
  }
}

__global__ __launch_bounds__(256) void k_passB(const unsigned int* __restrict__ bin,
                                               const int* __restrict__ boff, int NB, int N, int E,
                                               int* __restrict__ rowptr, float* __restrict__ dis,
                                               int* __restrict__ col) {
  __shared__ unsigned int colbuf[CAP_B];  // 48 KB
  __shared__ int lcnt[NPB], lofs2[NPB + 1], lpos[NPB];
  int b = blockIdx.x;
  int lo = b << NPB_SHIFT;
  int e0 = boff[b], e1 = boff[b + 1];
  int tot = e1 - e0;
  if (threadIdx.x < NPB) lcnt[threadIdx.x] = 0;
  __syncthreads();
  for (int i = threadIdx.x; i < tot; i += 256) {
    unsigned int v = bin[(size_t)e0 + i];
    atomicAdd(&lcnt[v >> 24], 1);
  }
  __syncthreads();
  if (threadIdx.x == 0) {
    int run = 0;
    for (int i = 0; i < NPB; i++) { lofs2[i] = run; run += lcnt[i]; }
    lofs2[NPB] = run;
  }
  __syncthreads();
  if (threadIdx.x < NPB) {
    int node = lo + threadIdx.x;
    if (node < N) {
      rowptr[node] = e0 + lofs2[threadIdx.x];
      dis[node] = rsqrtf((float)lcnt[threadIdx.x] + 1.0f);  // +1 self loop
    }
    lpos[threadIdx.x] = lofs2[threadIdx.x];
  }
  __syncthreads();
  for (int i = threadIdx.x; i < tot; i += 256) {
    unsigned int v = bin[(size_t)e0 + i];
    int idx = v >> 24;
    int p = atomicAdd(&lpos[idx], 1);
    unsigned int s = v & 0x00FFFFFFu;
    if (p < CAP_B) colbuf[p] = s;
    else col[(size_t)e0 + p] = (int)s;
  }
  __syncthreads();
  int cp = min(tot, CAP_B);
  for (int i = threadIdx.x; i < cp; i += 256)
    __builtin_nontemporal_store(colbuf[i], (unsigned int*)&col[(size_t)e0 + i]);
  if (b == 0 && threadIdx.x == 0) rowptr[N] = E;
}

// ---------------- W pre-pack into MFMA B-fragment order (fp16) ----------------
// B-frag for 16x16x32_f16: lane holds B[k = (lane>>4)*8 + j][n = lane&15].
// Wp flat index: ((ct*(K/32) + ks)*64 + lane)*8 + j, ct = n>>4, ks = k>>5.

template <int K, int N>
__device__ inline void packW_one(const float* __restrict__ W, _Float16* __restrict__ Wp,
                                 int idx) {
  int k = idx / N, n = idx % N;
  int ct = n >> 4, ks = k >> 5, q = (k >> 3) & 3, j = k & 7;
  int lane = (n & 15) + (q << 4);
  Wp[((((size_t)ct * (K / 32) + ks) * 64 + lane) << 3) + j] = (_Float16)W[idx];
}

__global__ __launch_bounds__(256) void k_packAll(const float* __restrict__ W1, _Float16* __restrict__ Wp1,
                                                 const float* __restrict__ W2, _Float16* __restrict__ Wp2,
                                                 const float* __restrict__ W3, _Float16* __restrict__ Wp3) {
  constexpr int S1 = IN_DIM * HID_DIM;            // 32768
  constexpr int S2 = S1 + HID_DIM * HID_DIM;      // 49152
  constexpr int S3 = S2 + HID_DIM * OUT_DIM;      // 57344
  int idx = blockIdx.x * 256 + threadIdx.x;
  if (idx < S1) packW_one<IN_DIM, HID_DIM>(W1, Wp1, idx);
  else if (idx < S2) packW_one<HID_DIM, HID_DIM>(W2, Wp2, idx - S1);
  else if (idx < S3) packW_one<HID_DIM, OUT_DIM>(W3, Wp3, idx - S2);
}

// ---------------- MFMA GEMM: out[r][c] = fp16(dis[r] * sum_k A[r][k]*W[k][c]) --------
// Block = 4 waves; wave w computes rows [blk*64 + w*16, +16) x all N cols.
// Wp is STAGED IN LDS once per block (shared by all 4 waves) — without this, every
// wave streams the whole packed W from L2: 16 segments x 64 instrs x 6250 waves
// ~ 6.4M cache-line segments for layer 1 (~58 us at the measured ~9 us/M-seg
// vector-memory segment-issue rate). Staging cuts B-segment traffic 16x.
// K=256 splits into two 32 KB k-halves to keep LDS at 32 KB (5 blocks/CU).

template <int K, int N, typename AT>
__global__ __launch_bounds__(256) void k_gemm_mfma(const AT* __restrict__ A,
                                                   const _Float16* __restrict__ Wp,
                                                   const float* __restrict__ dis,
                                                   __half* __restrict__ out, int M) {
  constexpr int CT = N / 16;   // 16-col tiles
  constexpr int KS = K / 32;   // 32-k steps
  constexpr int KH = (K * N * 2 > 32768) ? 2 : 1;  // k-halves for staging
  constexpr int KSH = KS / KH;                     // ks per half
  constexpr int NF4 = CT * KSH * 64;               // float4s staged per half (<=2048)
  __shared__ float4 wlds[NF4];                     // <=32 KB

  const int wave = threadIdx.x >> 6, lane = threadIdx.x & 63;
  const int q = lane >> 4, mlane = lane & 15;
  const int row0 = blockIdx.x * 64 + wave * 16;
  int arow = row0 + mlane;
  if (arow > M - 1) arow = M - 1;  // clamp (dup row, stores guarded)

  const float4* __restrict__ wsrc = (const float4*)Wp;

  floatx4 acc[CT];
#pragma unroll
  for (int c = 0; c < CT; c++) acc[c] = (floatx4){0.f, 0.f, 0.f, 0.f};

#pragma unroll
  for (int h = 0; h < KH; h++) {
    if (h) __syncthreads();  // all waves done reading previous half
    // stage half h: frag (c, ks=h*KSH+ksl) -> wlds[(c*KSH+ksl)*64 + j]
#pragma unroll
    for (int i = threadIdx.x; i < NF4; i += 256) {
      int c = i / (KSH * 64);
      int rem = i & (KSH * 64 - 1);
      wlds[i] = wsrc[(size_t)(c * KS + h * KSH) * 64 + rem];
    }
    __syncthreads();

#pragma unroll
    for (int ksl = 0; ksl < KSH; ksl++) {
      const int ks = h * KSH + ksl;
      half8 a;
      if constexpr (sizeof(AT) == 4) {
        const float* ap = &A[(size_t)arow * K + ks * 32 + q * 8];
        float4 f0 = *(const float4*)ap;
        float4 f1 = *(const float4*)(ap + 4);
        a[0] = (_Float16)f0.x; a[1] = (_Float16)f0.y;
        a[2] = (_Float16)f0.z; a[3] = (_Float16)f0.w;
        a[4] = (_Float16)f1.x; a[5] = (_Float16)f1.y;
        a[6] = (_Float16)f1.z; a[7] = (_Float16)f1.w;
      } else {
        a = *(const half8*)&A[(size_t)arow * K + ks * 32 + q * 8];
      }
#pragma unroll
      for (int c = 0; c < CT; c++) {
        half8 b = *(const half8*)&wlds[(c * KSH + ksl) * 64 + lane];
        acc[c] = __builtin_amdgcn_mfma_f32_16x16x32_f16(a, b, acc[c], 0, 0, 0);
      }
    }
  }

  // C/D layout: col = lane&15 (+ct*16), row = q*4 + r
  float dv[4]; int orow[4];
#pragma unroll
  for (int r = 0; r < 4; r++) {
    orow[r] = row0 + q * 4 + r;
    dv[r] = (orow[r] < M) ? dis[orow[r]] : 0.f;
  }
#pragma unroll
  for (int c = 0; c < CT; c++) {
    int cl = c * 16 + mlane;
#pragma unroll
    for (int r = 0; r < 4; r++)
      if (orow[r] < M)
        out[(size_t)orow[r] * N + cl] = __float2half_rn(dv[r] * acc[c][r]);
  }
}

// ---------------- aggregation F=128, quad-gather (at segment-issue wall) ----------------
// One wave per node. Lane = (r,c): r = lane>>4 (neighbor-in-quad), c = lane&15
// (16B chunk of the 256 B row). One gather instruction fetches FOUR neighbor rows.
// Measured wall: ~9-10 us per M 64B-segments; this layer = 12.8M segs ~= 115 us.

template <bool RELU>
__global__ __launch_bounds__(256) void k_agg128(const __half* __restrict__ g,
                                                const int* __restrict__ rowptr,
                                                const int* __restrict__ col,
                                                const float* __restrict__ dis,
                                                const float* __restrict__ bias,
                                                __half* __restrict__ out, int n) {
  const int lane = threadIdx.x & 63;
  const int r = lane >> 4;          // 0..3
  const int c = lane & 15;          // 0..15
  const int v = blockIdx.x * 4 + (threadIdx.x >> 6);
  if (v >= n) return;
  int p = rowptr[v], end = rowptr[v + 1];
  const float dv = dis[v];

  float acc[8];
#pragma unroll
  for (int i = 0; i < 8; i++) acc[i] = 0.f;
  if (r == 0) {  // self term, counted once
    half8 s = *(const half8*)&g[(size_t)v * 128 + c * 8];
#pragma unroll
    for (int i = 0; i < 8; i++) acc[i] += (float)s[i];
  }

  int rem = end - p;
  while (rem >= 8) {  // two quad-gathers in flight
    int u0 = __builtin_nontemporal_load(&col[p + r]);
    int u1 = __builtin_nontemporal_load(&col[p + 4 + r]);
    half8 t0 = *(const half8*)&g[(size_t)u0 * 128 + c * 8];
    half8 t1 = *(const half8*)&g[(size_t)u1 * 128 + c * 8];
#pragma unroll
    for (int i = 0; i < 8; i++) acc[i] += (float)t0[i];
#pragma unroll
    for (int i = 0; i < 8; i++) acc[i] += (float)t1[i];
    p += 8; rem -= 8;
  }
  if (rem >= 4) {
    int u0 = __builtin_nontemporal_load(&col[p + r]);
    half8 t0 = *(const half8*)&g[(size_t)u0 * 128 + c * 8];
#pragma unroll
    for (int i = 0; i < 8; i++) acc[i] += (float)t0[i];
    p += 4; rem -= 4;
  }
  if (rem > 0) {  // masked tail quad
    int rr = (r < rem) ? r : 0;
    int u0 = __builtin_nontemporal_load(&col[p + rr]);
    half8 t0 = *(const half8*)&g[(size_t)u0 * 128 + c * 8];
    float m = (r < rem) ? 1.f : 0.f;
#pragma unroll
    for (int i = 0; i < 8; i++) acc[i] = fmaf(m, (float)t0[i], acc[i]);
  }

  // merge the 4 row-groups (lanes c, c+16, c+32, c+48)
#pragma unroll
  for (int i = 0; i < 8; i++) {
    acc[i] += __shfl_xor(acc[i], 16);
    acc[i] += __shfl_xor(acc[i], 32);
  }

  if (r == 0) {
    half8 h;
#pragma unroll
    for (int i = 0; i < 8; i++) {
      float o = fmaf(dv, acc[i], bias[c * 8 + i]);
      if (RELU) o = fmaxf(o, 0.f);
      h[i] = (_Float16)o;
    }
    *(half8*)&out[(size_t)v * 128 + c * 8] = h;
  }
}

// ---------------- aggregation F=64, oct-gather, fp32 out, no relu ----------------

__global__ __launch_bounds__(256) void k_agg64(const __half* __restrict__ g,
                                               const int* __restrict__ rowptr,
                                               const int* __restrict__ col,
                                               const float* __restrict__ dis,
                                               const float* __restrict__ bias,
                                               float* __restrict__ out, int n) {
  const int lane = threadIdx.x & 63;
  const int r = lane >> 3;          // 0..7
  const int c = lane & 7;           // 0..7
  const int v = blockIdx.x * 4 + (threadIdx.x >> 6);
  if (v >= n) return;
  int p = rowptr[v], end = rowptr[v + 1];
  const float dv = dis[v];

  float acc[8];
#pragma unroll
  for (int i = 0; i < 8; i++) acc[i] = 0.f;
  if (r == 0) {
    half8 s = *(const half8*)&g[(size_t)v * 64 + c * 8];
#pragma unroll
    for (int i = 0; i < 8; i++) acc[i] += (float)s[i];
  }

  int rem = end - p;
  while (rem >= 16) {  // two oct-gathers in flight
    int u0 = __builtin_nontemporal_load(&col[p + r]);
    int u1 = __builtin_nontemporal_load(&col[p + 8 + r]);
    half8 t0 = *(const half8*)&g[(size_t)u0 * 64 + c * 8];
    half8 t1 = *(const half8*)&g[(size_t)u1 * 64 + c * 8];
#pragma unroll
    for (int i = 0; i < 8; i++) acc[i] += (float)t0[i];
#pragma unroll
    for (int i = 0; i < 8; i++) acc[i] += (float)t1[i];
    p += 16; rem -= 16;
  }
  if (rem >= 8) {
    int u0 = __builtin_nontemporal_load(&col[p + r]);
    half8 t0 = *(const half8*)&g[(size_t)u0 * 64 + c * 8];
#pragma unroll
    for (int i = 0; i < 8; i++) acc[i] += (float)t0[i];
    p += 8; rem -= 8;
  }
  if (rem > 0) {  // masked tail oct
    int rr = (r < rem) ? r : 0;
    int u0 = __builtin_nontemporal_load(&col[p + rr]);
    half8 t0 = *(const half8*)&g[(size_t)u0 * 64 + c * 8];
    float m = (r < rem) ? 1.f : 0.f;
#pragma unroll
    for (int i = 0; i < 8; i++) acc[i] = fmaf(m, (float)t0[i], acc[i]);
  }

  // merge the 8 row-groups (lanes differing in bits 3..5)
#pragma unroll
  for (int i = 0; i < 8; i++) {
    acc[i] += __shfl_xor(acc[i], 8);
    acc[i] += __shfl_xor(acc[i], 16);
    acc[i] += __shfl_xor(acc[i], 32);
  }

  if (r == 0) {
    float4 o0, o1;
    float ov[8];
#pragma unroll
    for (int i = 0; i < 8; i++) ov[i] = fmaf(dv, acc[i], bias[c * 8 + i]);
    o0.x = ov[0]; o0.y = ov[1]; o0.z = ov[2]; o0.w = ov[3];
    o1.x = ov[4]; o1.y = ov[5]; o1.z = ov[6]; o1.w = ov[7];
    *(float4*)&out[(size_t)v * 64 + c * 8]     = o0;
    *(float4*)&out[(size_t)v * 64 + c * 8 + 4] = o1;
  }
}

// ---------------- launch ----------------

extern "C" void kernel_launch(void* const* d_in, const int* in_sizes, int n_in,
                              void* d_out, int out_size, void* d_ws, size_t ws_size,
                              hipStream_t stream) {
  const float* x  = (const float*)d_in[0];
  const int*   ei = (const int*)d_in[1];
  const float* W1 = (const float*)d_in[2];
  const float* b1 = (const float*)d_in[3];
  const float* W2 = (const float*)d_in[4];
  const float* b2 = (const float*)d_in[5];
  const float* W3 = (const float*)d_in[6];
  const float* b3 = (const float*)d_in[7];
  float* outp = (float*)d_out;

  const int N = in_sizes[0] / IN_DIM;   // 100000
  const int E = in_sizes[1] / 2;        // 3200000
  const int* src = ei;
  const int* dst = ei + E;
  const int NB = (N + NPB - 1) >> NPB_SHIFT;  // 391 buckets

  char* w = (char*)d_ws;
  auto take = [&](size_t bytes) {
    char* r = w;
    w += (bytes + 255) & ~size_t(255);
    return r;
  };
  float*  dis    = (float*)take((size_t)N * 4);
  int*    rowptr = (int*)take((size_t)(N + 1) * 4);
  int*    bsize  = (int*)take((size_t)NB * 4);
  int*    boff   = (int*)take((size_t)(NB + 1) * 4);
  int*    gcur   = (int*)take((size_t)NB * 4);
  int*    col    = (int*)take((size_t)E * 4);
  unsigned int* bin = (unsigned int*)take((size_t)E * 4);
  _Float16* Wp1  = (_Float16*)take((size_t)IN_DIM * HID_DIM * 2);
  _Float16* Wp2  = (_Float16*)take((size_t)HID_DIM * HID_DIM * 2);
  _Float16* Wp3  = (_Float16*)take((size_t)HID_DIM * OUT_DIM * 2);
  __half* gbuf   = (__half*)take((size_t)N * 128 * 2);  // GEMM out / gather buffer
  __half* bufH   = (__half*)take((size_t)N * 128 * 2);  // agg out (next GEMM A)

  const int cb = (E + CHUNK - 1) / CHUNK;
  hipMemsetAsync(bsize, 0, (size_t)NB * 4, stream);
  hipLaunchKernelGGL(k_hist, dim3(cb), dim3(256), 0, stream, dst, E, NB, bsize);
  hipLaunchKernelGGL(k_scanb, dim3(1), dim3(512), 0, stream, bsize, NB, E, boff, gcur);
  hipLaunchKernelGGL(k_binA, dim3(cb), dim3(256), 0, stream, src, dst, E, NB, gcur, bin);
  hipLaunchKernelGGL(k_passB, dim3(NB), dim3(256), 0, stream, bin, boff, NB, N, E, rowptr, dis, col);

  hipLaunchKernelGGL(k_packAll, dim3((IN_DIM * HID_DIM + HID_DIM * HID_DIM + HID_DIM * OUT_DIM + 255) / 256),
                     dim3(256), 0, stream, W1, Wp1, W2, Wp2, W3, Wp3);

  const int gb = (N + 63) / 64;
  const int ab = (N + 3) / 4;
  // layer 1: gbuf = fp16(dis*(x@W1)) -> agg+relu -> bufH (fp16)
  hipLaunchKernelGGL((k_gemm_mfma<IN_DIM, HID_DIM, float>), dim3(gb), dim3(256), 0, stream, x, Wp1, dis, gbuf, N);
  hipLaunchKernelGGL((k_agg128<true>), dim3(ab), dim3(256), 0, stream, gbuf, rowptr, col, dis, b1, bufH, N);
  // layer 2
  hipLaunchKernelGGL((k_gemm_mfma<HID_DIM, HID_DIM, __half>), dim3(gb), dim3(256), 0, stream, bufH, Wp2, dis, gbuf, N);
  hipLaunchKernelGGL((k_agg128<true>), dim3(ab), dim3(256), 0, stream, gbuf, rowptr, col, dis, b2, bufH, N);
  // layer 3 (no relu), 64-dim, fp32 straight to d_out
  hipLaunchKernelGGL((k_gemm_mfma<HID_DIM, OUT_DIM, __half>), dim3(gb), dim3(256), 0, stream, bufH, Wp3, dis, gbuf, N);
  hipLaunchKernelGGL(k_agg64, dim3(ab), dim3(256), 0, stream, gbuf, rowptr, col, dis, b3, outp, N);
}

// Round 6
// 595.306 us; speedup vs baseline: 1.6729x; 1.0320x over previous
//
#include <hip/hip_runtime.h>
#include <hip/hip_fp16.h>

constexpr int IN_DIM  = 256;
constexpr int HID_DIM = 128;
constexpr int OUT_DIM = 64;

constexpr int NPB_SHIFT = 8;          // 256 nodes per bucket
constexpr int NPB   = 1 << NPB_SHIFT;
constexpr int NBMAX = 512;            // max buckets supported in LDS tables
constexpr int CHUNK = 4096;           // edges per binning block
constexpr int CAP_B = 12288;          // LDS col-stage capacity (48 KB)

typedef _Float16 half8 __attribute__((ext_vector_type(8)));
typedef float floatx4 __attribute__((ext_vector_type(4)));

// ---------------- CSR build via bucketed counting sort ----------------

__global__ __launch_bounds__(256) void k_hist(const int* __restrict__ dst, int E, int NB,
                                              int* __restrict__ bsize) {
  __shared__ int h[NBMAX];
  for (int i = threadIdx.x; i < NB; i += 256) h[i] = 0;
  __syncthreads();
  int e0 = blockIdx.x * CHUNK;
  int e1 = min(e0 + CHUNK, E);
  for (int e = e0 + threadIdx.x; e < e1; e += 256) {
    int d = __builtin_nontemporal_load(&dst[e]);
    atomicAdd(&h[d >> NPB_SHIFT], 1);
  }
  __syncthreads();
  for (int b = threadIdx.x; b < NB; b += 256) {
    int c = h[b];
    if (c) atomicAdd(&bsize[b], c);
  }
}

__global__ __launch_bounds__(512) void k_scanb(const int* __restrict__ bsize, int NB, int E,
                                               int* __restrict__ boff, int* __restrict__ gcur) {
  __shared__ int sh[NBMAX + 1];
  for (int i = threadIdx.x; i < NB; i += 512) sh[i] = bsize[i];
  __syncthreads();
  if (threadIdx.x == 0) {
    int run = 0;
    for (int b = 0; b < NB; b++) { int v = sh[b]; sh[b] = run; run += v; }
    sh[NB] = run;
  }
  __syncthreads();
  for (int i = threadIdx.x; i < NB; i += 512) { boff[i] = sh[i]; gcur[i] = sh[i]; }
  if (threadIdx.x == 0) boff[NB] = sh[NB];
}

// bin entry: 4 bytes = (dst&255)<<24 | src  (src < 2^24; bucket from position)
__global__ __launch_bounds__(256) void k_binA(const int* __restrict__ src,
                                              const int* __restrict__ dst, int E, int NB,
                                              int* __restrict__ gcur,
                                              unsigned int* __restrict__ bin) {
  __shared__ unsigned int sbuf[CHUNK];      // 16 KB
  __shared__ unsigned short sbb[CHUNK];     // 8 KB (bucket per staged entry)
  __shared__ int h[NBMAX], lofs[NBMAX], wofs[NBMAX], hcur[NBMAX];
  for (int i = threadIdx.x; i < NB; i += 256) h[i] = 0;
  __syncthreads();
  int e0 = blockIdx.x * CHUNK;
  int e1 = min(e0 + CHUNK, E);
  for (int e = e0 + threadIdx.x; e < e1; e += 256) {
    int d = __builtin_nontemporal_load(&dst[e]);
    atomicAdd(&h[d >> NPB_SHIFT], 1);
  }
  __syncthreads();
  for (int b = threadIdx.x; b < NB; b += 256) {
    int c = h[b];
    if (c) wofs[b] = atomicAdd(&gcur[b], c);
  }
  if (threadIdx.x == 0) {
    int run = 0;
    for (int b = 0; b < NB; b++) { lofs[b] = run; run += h[b]; }
  }
  __syncthreads();
  for (int b = threadIdx.x; b < NB; b += 256) hcur[b] = lofs[b];
  __syncthreads();
  for (int e = e0 + threadIdx.x; e < e1; e += 256) {
    int d = dst[e];
    int s = src[e];
    int b = d >> NPB_SHIFT;
    int p = atomicAdd(&hcur[b], 1);
    sbuf[p] = ((unsigned int)(d & (NPB - 1)) << 24) | (unsigned int)s;
    sbb[p] = (unsigned short)b;
  }
  __syncthreads();
  int total = e1 - e0;
  for (int i = threadIdx.x; i < total; i += 256) {
    int b = sbb[i];
    bin[(size_t)wofs[b] + (i - lofs[b])] = sbuf[i];
  }
}

__global__ __launch_bounds__(256) void k_passB(const unsigned int* __restrict__ bin,
                                               const int* __restrict__ boff, int NB, int N, int E,
                                               int* __restrict__ rowptr, float* __restrict__ dis,
                                               int* __restrict__ col) {
  __shared__ unsigned int colbuf[CAP_B];  // 48 KB
  __shared__ int lcnt[NPB], lofs2[NPB + 1], lpos[NPB];
  int b = blockIdx.x;
  int lo = b << NPB_SHIFT;
  int e0 = boff[b], e1 = boff[b + 1];
  int tot = e1 - e0;
  if (threadIdx.x < NPB) lcnt[threadIdx.x] = 0;
  __syncthreads();
  for (int i = threadIdx.x; i < tot; i += 256) {
    unsigned int v = bin[(size_t)e0 + i];
    atomicAdd(&lcnt[v >> 24], 1);
  }
  __syncthreads();
  if (threadIdx.x == 0) {
    int run = 0;
    for (int i = 0; i < NPB; i++) { lofs2[i] = run; run += lcnt[i]; }
    lofs2[NPB] = run;
  }
  __syncthreads();
  if (threadIdx.x < NPB) {
    int node = lo + threadIdx.x;
    if (node < N) {
      rowptr[node] = e0 + lofs2[threadIdx.x];
      dis[node] = rsqrtf((float)lcnt[threadIdx.x] + 1.0f);  // +1 self loop
    }
    lpos[threadIdx.x] = lofs2[threadIdx.x];
  }
  __syncthreads();
  for (int i = threadIdx.x; i < tot; i += 256) {
    unsigned int v = bin[(size_t)e0 + i];
    int idx = v >> 24;
    int p = atomicAdd(&lpos[idx], 1);
    unsigned int s = v & 0x00FFFFFFu;
    if (p < CAP_B) colbuf[p] = s;
    else col[(size_t)e0 + p] = (int)s;
  }
  __syncthreads();
  int cp = min(tot, CAP_B);
  for (int i = threadIdx.x; i < cp; i += 256)
    __builtin_nontemporal_store(colbuf[i], (unsigned int*)&col[(size_t)e0 + i]);
  if (b == 0 && threadIdx.x == 0) rowptr[N] = E;
}

// ---------------- W pre-pack into MFMA B-fragment order (fp16) ----------------
// B-frag for 16x16x32_f16: lane holds B[k = (lane>>4)*8 + j][n = lane&15].
// Wp flat index: ((ct*(K/32) + ks)*64 + lane)*8 + j, ct = n>>4, ks = k>>5.

template <int K, int N>
__device__ inline void packW_one(const float* __restrict__ W, _Float16* __restrict__ Wp,
                                 int idx) {
  int k = idx / N, n = idx % N;
  int ct = n >> 4, ks = k >> 5, q = (k >> 3) & 3, j = k & 7;
  int lane = (n & 15) + (q << 4);
  Wp[((((size_t)ct * (K / 32) + ks) * 64 + lane) << 3) + j] = (_Float16)W[idx];
}

__global__ __launch_bounds__(256) void k_packAll(const float* __restrict__ W1, _Float16* __restrict__ Wp1,
                                                 const float* __restrict__ W2, _Float16* __restrict__ Wp2,
                                                 const float* __restrict__ W3, _Float16* __restrict__ Wp3) {
  constexpr int S1 = IN_DIM * HID_DIM;            // 32768
  constexpr int S2 = S1 + HID_DIM * HID_DIM;      // 49152
  constexpr int S3 = S2 + HID_DIM * OUT_DIM;      // 57344
  int idx = blockIdx.x * 256 + threadIdx.x;
  if (idx < S1) packW_one<IN_DIM, HID_DIM>(W1, Wp1, idx);
  else if (idx < S2) packW_one<HID_DIM, HID_DIM>(W2, Wp2, idx - S1);
  else if (idx < S3) packW_one<HID_DIM, OUT_DIM>(W3, Wp3, idx - S2);
}

// ---------------- MFMA GEMM: out[r][c] = fp16(dis[r] * sum_k A[r][k]*W[k][c]) --------
// Block = 4 waves; wave w computes rows [blk*64 + w*16, +16) x all N cols.
// Wp staged in LDS once per block (r5: small but real win, keep).

template <int K, int N, typename AT>
__global__ __launch_bounds__(256) void k_gemm_mfma(const AT* __restrict__ A,
                                                   const _Float16* __restrict__ Wp,
                                                   const float* __restrict__ dis,
                                                   __half* __restrict__ out, int M) {
  constexpr int CT = N / 16;   // 16-col tiles
  constexpr int KS = K / 32;   // 32-k steps
  constexpr int KH = (K * N * 2 > 32768) ? 2 : 1;  // k-halves for staging
  constexpr int KSH = KS / KH;                     // ks per half
  constexpr int NF4 = CT * KSH * 64;               // float4s staged per half (<=2048)
  __shared__ float4 wlds[NF4];                     // <=32 KB

  const int wave = threadIdx.x >> 6, lane = threadIdx.x & 63;
  const int q = lane >> 4, mlane = lane & 15;
  const int row0 = blockIdx.x * 64 + wave * 16;
  int arow = row0 + mlane;
  if (arow > M - 1) arow = M - 1;  // clamp (dup row, stores guarded)

  const float4* __restrict__ wsrc = (const float4*)Wp;

  floatx4 acc[CT];
#pragma unroll
  for (int c = 0; c < CT; c++) acc[c] = (floatx4){0.f, 0.f, 0.f, 0.f};

#pragma unroll
  for (int h = 0; h < KH; h++) {
    if (h) __syncthreads();  // all waves done reading previous half
#pragma unroll
    for (int i = threadIdx.x; i < NF4; i += 256) {
      int c = i / (KSH * 64);
      int rem = i & (KSH * 64 - 1);
      wlds[i] = wsrc[(size_t)(c * KS + h * KSH) * 64 + rem];
    }
    __syncthreads();

#pragma unroll
    for (int ksl = 0; ksl < KSH; ksl++) {
      const int ks = h * KSH + ksl;
      half8 a;
      if constexpr (sizeof(AT) == 4) {
        const float* ap = &A[(size_t)arow * K + ks * 32 + q * 8];
        float4 f0 = *(const float4*)ap;
        float4 f1 = *(const float4*)(ap + 4);
        a[0] = (_Float16)f0.x; a[1] = (_Float16)f0.y;
        a[2] = (_Float16)f0.z; a[3] = (_Float16)f0.w;
        a[4] = (_Float16)f1.x; a[5] = (_Float16)f1.y;
        a[6] = (_Float16)f1.z; a[7] = (_Float16)f1.w;
      } else {
        a = *(const half8*)&A[(size_t)arow * K + ks * 32 + q * 8];
      }
#pragma unroll
      for (int c = 0; c < CT; c++) {
        half8 b = *(const half8*)&wlds[(c * KSH + ksl) * 64 + lane];
        acc[c] = __builtin_amdgcn_mfma_f32_16x16x32_f16(a, b, acc[c], 0, 0, 0);
      }
    }
  }

  float dv[4]; int orow[4];
#pragma unroll
  for (int r = 0; r < 4; r++) {
    orow[r] = row0 + q * 4 + r;
    dv[r] = (orow[r] < M) ? dis[orow[r]] : 0.f;
  }
#pragma unroll
  for (int c = 0; c < CT; c++) {
    int cl = c * 16 + mlane;
#pragma unroll
    for (int r = 0; r < 4; r++)
      if (orow[r] < M)
        out[(size_t)orow[r] * N + cl] = __float2half_rn(dv[r] * acc[c][r]);
  }
}

// ---------------- aggregation F=128, quad-gather + shfl-distributed col ----------------
// One wave per node; lane = (r = lane>>4 neighbor-in-quad, c = lane&15 16B chunk).
// Col indices: ONE 64-wide VMEM load per 64 neighbors (cv = col[p+lane]), then
// __shfl (ds_bpermute, LDS pipe) distributes them — removes ~750K TA-path VMEM
// instrs per layer (fitted cost ~11 cyc/instr/CU).
// Split into two half-node dispatches (v0 param) so rocprof top-5 surfaces the
// next-tier kernels hidden behind this one.

template <bool RELU>
__global__ __launch_bounds__(256) void k_agg128(const __half* __restrict__ g,
                                                const int* __restrict__ rowptr,
                                                const int* __restrict__ col,
                                                const float* __restrict__ dis,
                                                const float* __restrict__ bias,
                                                __half* __restrict__ out, int n, int v0) {
  const int lane = threadIdx.x & 63;
  const int r = lane >> 4;          // 0..3
  const int c = lane & 15;          // 0..15
  const int v = v0 + blockIdx.x * 4 + (threadIdx.x >> 6);
  if (v >= n) return;
  int p = rowptr[v], end = rowptr[v + 1];
  const float dv = dis[v];

  float acc[8];
#pragma unroll
  for (int i = 0; i < 8; i++) acc[i] = 0.f;
  if (r == 0) {  // self term, counted once
    half8 s = *(const half8*)&g[(size_t)v * 128 + c * 8];
#pragma unroll
    for (int i = 0; i < 8; i++) acc[i] += (float)s[i];
  }

  while (p < end) {
    int navail = end - p;
    if (navail > 64) navail = 64;
    int cv = __builtin_nontemporal_load(&col[p + (lane < navail ? lane : 0)]);
    int done = 0;
    while (navail - done >= 8) {  // two quad-gathers in flight
      int u0 = __shfl(cv, done + r);
      int u1 = __shfl(cv, done + 4 + r);
      half8 t0 = *(const half8*)&g[(size_t)u0 * 128 + c * 8];
      half8 t1 = *(const half8*)&g[(size_t)u1 * 128 + c * 8];
#pragma unroll
      for (int i = 0; i < 8; i++) acc[i] += (float)t0[i];
#pragma unroll
      for (int i = 0; i < 8; i++) acc[i] += (float)t1[i];
      done += 8;
    }
    int remn = navail - done;  // 0..7
    if (remn > 0) {
      int m0 = remn < 4 ? remn : 4;
      int u0 = __shfl(cv, done + (r < m0 ? r : 0));
      half8 t0 = *(const half8*)&g[(size_t)u0 * 128 + c * 8];
      float k0 = (r < m0) ? 1.f : 0.f;
#pragma unroll
      for (int i = 0; i < 8; i++) acc[i] = fmaf(k0, (float)t0[i], acc[i]);
      if (remn > 4) {
        int m1 = remn - 4;
        int u1 = __shfl(cv, done + 4 + (r < m1 ? r : 0));
        half8 t1 = *(const half8*)&g[(size_t)u1 * 128 + c * 8];
        float k1 = (r < m1) ? 1.f : 0.f;
#pragma unroll
        for (int i = 0; i < 8; i++) acc[i] = fmaf(k1, (float)t1[i], acc[i]);
      }
    }
    p += navail;
  }

  // merge the 4 row-groups (lanes c, c+16, c+32, c+48)
#pragma unroll
  for (int i = 0; i < 8; i++) {
    acc[i] += __shfl_xor(acc[i], 16);
    acc[i] += __shfl_xor(acc[i], 32);
  }

  if (r == 0) {
    half8 h;
#pragma unroll
    for (int i = 0; i < 8; i++) {
      float o = fmaf(dv, acc[i], bias[c * 8 + i]);
      if (RELU) o = fmaxf(o, 0.f);
      h[i] = (_Float16)o;
    }
    *(half8*)&out[(size_t)v * 128 + c * 8] = h;
  }
}

// ---------------- aggregation F=64, oct-gather + shfl-distributed col ----------------

__global__ __launch_bounds__(256) void k_agg64(const __half* __restrict__ g,
                                               const int* __restrict__ rowptr,
                                               const int* __restrict__ col,
                                               const float* __restrict__ dis,
                                               const float* __restrict__ bias,
                                               float* __restrict__ out, int n) {
  const int lane = threadIdx.x & 63;
  const int r = lane >> 3;          // 0..7
  const int c = lane & 7;           // 0..7
  const int v = blockIdx.x * 4 + (threadIdx.x >> 6);
  if (v >= n) return;
  int p = rowptr[v], end = rowptr[v + 1];
  const float dv = dis[v];

  float acc[8];
#pragma unroll
  for (int i = 0; i < 8; i++) acc[i] = 0.f;
  if (r == 0) {
    half8 s = *(const half8*)&g[(size_t)v * 64 + c * 8];
#pragma unroll
    for (int i = 0; i < 8; i++) acc[i] += (float)s[i];
  }

  while (p < end) {
    int navail = end - p;
    if (navail > 64) navail = 64;
    int cv = __builtin_nontemporal_load(&col[p + (lane < navail ? lane : 0)]);
    int done = 0;
    while (navail - done >= 16) {  // two oct-gathers in flight
      int u0 = __shfl(cv, done + r);
      int u1 = __shfl(cv, done + 8 + r);
      half8 t0 = *(const half8*)&g[(size_t)u0 * 64 + c * 8];
      half8 t1 = *(const half8*)&g[(size_t)u1 * 64 + c * 8];
#pragma unroll
      for (int i = 0; i < 8; i++) acc[i] += (float)t0[i];
#pragma unroll
      for (int i = 0; i < 8; i++) acc[i] += (float)t1[i];
      done += 16;
    }
    int remn = navail - done;  // 0..15
    if (remn > 0) {
      int m0 = remn < 8 ? remn : 8;
      int u0 = __shfl(cv, done + (r < m0 ? r : 0));
      half8 t0 = *(const half8*)&g[(size_t)u0 * 64 + c * 8];
      float k0 = (r < m0) ? 1.f : 0.f;
#pragma unroll
      for (int i = 0; i < 8; i++) acc[i] = fmaf(k0, (float)t0[i], acc[i]);
      if (remn > 8) {
        int m1 = remn - 8;
        int u1 = __shfl(cv, done + 8 + (r < m1 ? r : 0));
        half8 t1 = *(const half8*)&g[(size_t)u1 * 64 + c * 8];
        float k1 = (r < m1) ? 1.f : 0.f;
#pragma unroll
        for (int i = 0; i < 8; i++) acc[i] = fmaf(k1, (float)t1[i], acc[i]);
      }
    }
    p += navail;
  }

  // merge the 8 row-groups (lanes differing in bits 3..5)
#pragma unroll
  for (int i = 0; i < 8; i++) {
    acc[i] += __shfl_xor(acc[i], 8);
    acc[i] += __shfl_xor(acc[i], 16);
    acc[i] += __shfl_xor(acc[i], 32);
  }

  if (r == 0) {
    float4 o0, o1;
    float ov[8];
#pragma unroll
    for (int i = 0; i < 8; i++) ov[i] = fmaf(dv, acc[i], bias[c * 8 + i]);
    o0.x = ov[0]; o0.y = ov[1]; o0.z = ov[2]; o0.w = ov[3];
    o1.x = ov[4]; o1.y = ov[5]; o1.z = ov[6]; o1.w = ov[7];
    *(float4*)&out[(size_t)v * 64 + c * 8]     = o0;
    *(float4*)&out[(size_t)v * 64 + c * 8 + 4] = o1;
  }
}

// ---------------- launch ----------------

extern "C" void kernel_launch(void* const* d_in, const int* in_sizes, int n_in,
                              void* d_out, int out_size, void* d_ws, size_t ws_size,
                              hipStream_t stream) {
  const float* x  = (const float*)d_in[0];
  const int*   ei = (const int*)d_in[1];
  const float* W1 = (const float*)d_in[2];
  const float* b1 = (const float*)d_in[3];
  const float* W2 = (const float*)d_in[4];
  const float* b2 = (const float*)d_in[5];
  const float* W3 = (const float*)d_in[6];
  const float* b3 = (const float*)d_in[7];
  float* outp = (float*)d_out;

  const int N = in_sizes[0] / IN_DIM;   // 100000
  const int E = in_sizes[1] / 2;        // 3200000
  const int* src = ei;
  const int* dst = ei + E;
  const int NB = (N + NPB - 1) >> NPB_SHIFT;  // 391 buckets

  char* w = (char*)d_ws;
  auto take = [&](size_t bytes) {
    char* r = w;
    w += (bytes + 255) & ~size_t(255);
    return r;
  };
  float*  dis    = (float*)take((size_t)N * 4);
  int*    rowptr = (int*)take((size_t)(N + 1) * 4);
  int*    bsize  = (int*)take((size_t)NB * 4);
  int*    boff   = (int*)take((size_t)(NB + 1) * 4);
  int*    gcur   = (int*)take((size_t)NB * 4);
  int*    col    = (int*)take((size_t)E * 4);
  unsigned int* bin = (unsigned int*)take((size_t)E * 4);
  _Float16* Wp1  = (_Float16*)take((size_t)IN_DIM * HID_DIM * 2);
  _Float16* Wp2  = (_Float16*)take((size_t)HID_DIM * HID_DIM * 2);
  _Float16* Wp3  = (_Float16*)take((size_t)HID_DIM * OUT_DIM * 2);
  __half* gbuf   = (__half*)take((size_t)N * 128 * 2);  // GEMM out / gather buffer
  __half* bufH   = (__half*)take((size_t)N * 128 * 2);  // agg out (next GEMM A)

  const int cb = (E + CHUNK - 1) / CHUNK;
  hipMemsetAsync(bsize, 0, (size_t)NB * 4, stream);
  hipLaunchKernelGGL(k_hist, dim3(cb), dim3(256), 0, stream, dst, E, NB, bsize);
  hipLaunchKernelGGL(k_scanb, dim3(1), dim3(512), 0, stream, bsize, NB, E, boff, gcur);
  hipLaunchKernelGGL(k_binA, dim3(cb), dim3(256), 0, stream, src, dst, E, NB, gcur, bin);
  hipLaunchKernelGGL(k_passB, dim3(NB), dim3(256), 0, stream, bin, boff, NB, N, E, rowptr, dis, col);

  hipLaunchKernelGGL(k_packAll, dim3((IN_DIM * HID_DIM + HID_DIM * HID_DIM + HID_DIM * OUT_DIM + 255) / 256),
                     dim3(256), 0, stream, W1, Wp1, W2, Wp2, W3, Wp3);

  const int gb = (N + 63) / 64;
  const int ab = (N + 3) / 4;
  const int nh = (N + 1) / 2;               // half-node split for agg128
  const int ab1 = (nh + 3) / 4;
  const int ab2 = (N - nh + 3) / 4;
  // layer 1: gbuf = fp16(dis*(x@W1)) -> agg+relu (two half dispatches) -> bufH
  hipLaunchKernelGGL((k_gemm_mfma<IN_DIM, HID_DIM, float>), dim3(gb), dim3(256), 0, stream, x, Wp1, dis, gbuf, N);
  hipLaunchKernelGGL((k_agg128<true>), dim3(ab1), dim3(256), 0, stream, gbuf, rowptr, col, dis, b1, bufH, N, 0);
  hipLaunchKernelGGL((k_agg128<true>), dim3(ab2), dim3(256), 0, stream, gbuf, rowptr, col, dis, b1, bufH, N, nh);
  // layer 2
  hipLaunchKernelGGL((k_gemm_mfma<HID_DIM, HID_DIM, __half>), dim3(gb), dim3(256), 0, stream, bufH, Wp2, dis, gbuf, N);
  hipLaunchKernelGGL((k_agg128<true>), dim3(ab1), dim3(256), 0, stream, gbuf, rowptr, col, dis, b2, bufH, N, 0);
  hipLaunchKernelGGL((k_agg128<true>), dim3(ab2), dim3(256), 0, stream, gbuf, rowptr, col, dis, b2, bufH, N, nh);
  // layer 3 (no relu), 64-dim, fp32 straight to d_out
  hipLaunchKernelGGL((k_gemm_mfma<HID_DIM, OUT_DIM, __half>), dim3(gb), dim3(256), 0, stream, bufH, Wp3, dis, gbuf, N);
  hipLaunchKernelGGL(k_agg64, dim3(ab), dim3(256), 0, stream, gbuf, rowptr, col, dis, b3, outp, N);
}